// Round 3
// baseline (2250.342 us; speedup 1.0000x reference)
//
#include <hip/hip_runtime.h>
#include <math.h>

#define N_NODES 100000
#define N_EDGES 3200000
#define D_FEAT 128
#define H1 32
#define H2 16
#define NC 8

// ---------------- edge-index dtype detect + convert ----------------
// If the device buffer is little-endian int64 with values < 2^31, every odd
// int32 word is 0. With int32 data the odd words are random node ids.

__global__ void k_detect(const int* __restrict__ ei, int* __restrict__ meta) {
    __shared__ int red[256];
    int v = 0;
    for (int i = threadIdx.x; i < 1024; i += 256) v |= ei[2 * i + 1];
    red[threadIdx.x] = v;
    __syncthreads();
    for (int s = 128; s > 0; s >>= 1) {
        if (threadIdx.x < (unsigned)s) red[threadIdx.x] |= red[threadIdx.x + s];
        __syncthreads();
    }
    if (threadIdx.x == 0) meta[0] = (red[0] == 0) ? 1 : 0;  // 1 => int64
}

__global__ void k_convert(const int* __restrict__ ei, const int* __restrict__ meta,
                          int* __restrict__ src32, int* __restrict__ dst32) {
    const int e = blockIdx.x * blockDim.x + threadIdx.x;
    if (e >= N_EDGES) return;
    if (meta[0]) {  // int64: value at low word
        src32[e] = ei[2 * e];
        dst32[e] = ei[2 * N_EDGES + 2 * e];
    } else {        // int32
        src32[e] = ei[e];
        dst32[e] = ei[N_EDGES + e];
    }
}

// ---------------- degree / norm ----------------

__global__ void k_deg_init(float* __restrict__ deg) {
    int v = blockIdx.x * blockDim.x + threadIdx.x;
    if (v < N_NODES) deg[v] = 1.0f;  // self-loop
}

__global__ void k_deg_count(const int* __restrict__ dst, float* __restrict__ deg) {
    int e = blockIdx.x * blockDim.x + threadIdx.x;
    if (e < N_EDGES) atomicAdd(&deg[dst[e]], 1.0f);
}

__global__ void k_dinv(float* __restrict__ deg) {
    int v = blockIdx.x * blockDim.x + threadIdx.x;
    if (v < N_NODES) deg[v] = rsqrtf(deg[v]);  // deg >= 1 always
}

// ---------------- layer 1 linear: t1 = x @ W1 ; a1 = t1 * dinv^2 (self loop) ----

__global__ __launch_bounds__(256) void k_gemm1(const float* __restrict__ x,
                                               const float* __restrict__ W1,
                                               const float* __restrict__ dinv,
                                               float* __restrict__ t1,
                                               float* __restrict__ a1) {
    __shared__ float Ws[D_FEAT * H1];   // 16 KB
    __shared__ float xs[8][D_FEAT];     // 4 KB
    const int tid = threadIdx.x;
    for (int i = tid; i < D_FEAT * H1; i += 256) Ws[i] = W1[i];
    const int row0 = blockIdx.x * 8;    // 100000/8 = 12500 exact
    const float4* xg = (const float4*)(x + (size_t)row0 * D_FEAT);
    ((float4*)&xs[0][0])[tid] = xg[tid];
    __syncthreads();
    const int r = tid >> 5;   // 0..7
    const int j = tid & 31;   // 0..31
    float acc = 0.0f;
#pragma unroll 8
    for (int k = 0; k < D_FEAT; ++k)
        acc = fmaf(xs[r][k], Ws[k * H1 + j], acc);
    const int v = row0 + r;
    const float di = dinv[v];
    t1[(size_t)v * H1 + j] = acc;
    a1[(size_t)v * H1 + j] = acc * di * di;   // self-loop init (also un-poisons ws)
}

// ---------------- edge aggregation, layer 1 (32 feats, 8 lanes/edge) ----------

__global__ void k_agg1(const int* __restrict__ src, const int* __restrict__ dst,
                       const float* __restrict__ dinv,
                       const float* __restrict__ t1, float* __restrict__ a1) {
    const int t = blockIdx.x * blockDim.x + threadIdx.x;
    const int e = t >> 3;
    const int l = t & 7;
    if (e >= N_EDGES) return;
    const int s = src[e];
    const int d = dst[e];
    const float nrm = dinv[s] * dinv[d];
    const float4 vv = *(const float4*)(t1 + (size_t)s * H1 + l * 4);
    float* out = a1 + (size_t)d * H1 + l * 4;
    atomicAdd(out + 0, vv.x * nrm);
    atomicAdd(out + 1, vv.y * nrm);
    atomicAdd(out + 2, vv.z * nrm);
    atomicAdd(out + 3, vv.w * nrm);
}

// ---------------- layer 2 linear: h1 = relu(a1+b1); t2 = h1 @ W2 ; a2 init ----

__global__ __launch_bounds__(256) void k_gemm2(const float* __restrict__ a1,
                                               const float* __restrict__ b1,
                                               const float* __restrict__ W2,
                                               const float* __restrict__ dinv,
                                               float* __restrict__ t2,
                                               float* __restrict__ a2) {
    __shared__ float Ws[H1 * H2];   // 512 floats
    __shared__ float hs[16 * H1];   // 512 floats
    const int tid = threadIdx.x;
    // FIX(R3): was `if (tid < H1*H2)` with blockDim=256 — Ws[256..511] (rows
    // 16..31 of W2) were NEVER loaded -> uninitialized LDS in the matmul.
    // Explains both the ~0.2 absmax and the run-to-run nondeterminism.
    for (int i = tid; i < H1 * H2; i += 256) Ws[i] = W2[i];
    const int row0 = blockIdx.x * 16;   // 100000/16 = 6250 exact
    for (int i = tid; i < 16 * H1; i += 256) {
        const int col = i & (H1 - 1);
        hs[i] = fmaxf(a1[(size_t)row0 * H1 + i] + b1[col], 0.0f);
    }
    __syncthreads();
    const int r = tid >> 4;   // 0..15
    const int j = tid & 15;   // 0..15
    float acc = 0.0f;
#pragma unroll
    for (int k = 0; k < H1; ++k)
        acc = fmaf(hs[r * H1 + k], Ws[k * H2 + j], acc);
    const int v = row0 + r;
    const float di = dinv[v];
    t2[(size_t)v * H2 + j] = acc;
    a2[(size_t)v * H2 + j] = acc * di * di;
}

// ---------------- edge aggregation, layer 2 (16 feats, 4 lanes/edge) ----------

__global__ void k_agg2(const int* __restrict__ src, const int* __restrict__ dst,
                       const float* __restrict__ dinv,
                       const float* __restrict__ t2, float* __restrict__ a2) {
    const int t = blockIdx.x * blockDim.x + threadIdx.x;
    const int e = t >> 2;
    const int l = t & 3;
    if (e >= N_EDGES) return;
    const int s = src[e];
    const int d = dst[e];
    const float nrm = dinv[s] * dinv[d];
    const float4 vv = *(const float4*)(t2 + (size_t)s * H2 + l * 4);
    float* out = a2 + (size_t)d * H2 + l * 4;
    atomicAdd(out + 0, vv.x * nrm);
    atomicAdd(out + 1, vv.y * nrm);
    atomicAdd(out + 2, vv.z * nrm);
    atomicAdd(out + 3, vv.w * nrm);
}

// ---------------- final: relu(a2+b2) @ Wc + bc -> log_softmax ----------------

__global__ void k_final(const float* __restrict__ a2, const float* __restrict__ b2,
                        const float* __restrict__ Wc, const float* __restrict__ bc,
                        float* __restrict__ out) {
    const int v = blockIdx.x * blockDim.x + threadIdx.x;
    if (v >= N_NODES) return;
    float h[H2];
    const float4* ap = (const float4*)(a2 + (size_t)v * H2);
#pragma unroll
    for (int q = 0; q < 4; ++q) {
        const float4 p = ap[q];
        h[q * 4 + 0] = fmaxf(p.x + b2[q * 4 + 0], 0.0f);
        h[q * 4 + 1] = fmaxf(p.y + b2[q * 4 + 1], 0.0f);
        h[q * 4 + 2] = fmaxf(p.z + b2[q * 4 + 2], 0.0f);
        h[q * 4 + 3] = fmaxf(p.w + b2[q * 4 + 3], 0.0f);
    }
    float lg[NC];
#pragma unroll
    for (int j = 0; j < NC; ++j) lg[j] = bc[j];
#pragma unroll
    for (int k = 0; k < H2; ++k) {
        const float hk = h[k];
#pragma unroll
        for (int j = 0; j < NC; ++j)
            lg[j] = fmaf(hk, Wc[k * NC + j], lg[j]);
    }
    float m = lg[0];
#pragma unroll
    for (int j = 1; j < NC; ++j) m = fmaxf(m, lg[j]);
    float s = 0.0f;
#pragma unroll
    for (int j = 0; j < NC; ++j) s += expf(lg[j] - m);
    const float lse = logf(s);
    float4 o0, o1;
    o0.x = lg[0] - m - lse; o0.y = lg[1] - m - lse;
    o0.z = lg[2] - m - lse; o0.w = lg[3] - m - lse;
    o1.x = lg[4] - m - lse; o1.y = lg[5] - m - lse;
    o1.z = lg[6] - m - lse; o1.w = lg[7] - m - lse;
    float4* op = (float4*)(out + (size_t)v * NC);
    op[0] = o0; op[1] = o1;
}

// ---------------- host launch ----------------

extern "C" void kernel_launch(void* const* d_in, const int* in_sizes, int n_in,
                              void* d_out, int out_size, void* d_ws, size_t ws_size,
                              hipStream_t stream) {
    const float* x   = (const float*)d_in[0];
    const int*   ei  = (const int*)d_in[1];     // [2, E]; int64 or int32 (detected)
    const float* W1  = (const float*)d_in[2];
    const float* b1  = (const float*)d_in[3];
    const float* W2  = (const float*)d_in[4];
    const float* b2  = (const float*)d_in[5];
    const float* Wc  = (const float*)d_in[6];
    const float* bc  = (const float*)d_in[7];
    float* out = (float*)d_out;

    // workspace layout (4-byte units, all 16B-aligned):
    //  meta(16) | src32 (3.2M) | dst32 (3.2M) | deg (100000) | t1 (3.2M) |
    //  a1 (3.2M) | t2 (1.6M)   ; a2 aliases t1 (dead after k_agg1)
    int*   meta  = (int*)d_ws;
    int*   src32 = meta + 16;
    int*   dst32 = src32 + N_EDGES;
    float* deg   = (float*)(dst32 + N_EDGES);
    float* t1    = deg + N_NODES;
    float* a1    = t1 + (size_t)N_NODES * H1;
    float* t2    = a1 + (size_t)N_NODES * H1;
    float* a2    = t1;   // t1 dead after k_agg1; k_gemm2 reads only a1

    const int B = 256;
    k_detect <<<1, B, 0, stream>>>(ei, meta);
    k_convert<<<(N_EDGES + B - 1) / B, B, 0, stream>>>(ei, meta, src32, dst32);

    k_deg_init <<<(N_NODES + B - 1) / B, B, 0, stream>>>(deg);
    k_deg_count<<<(N_EDGES + B - 1) / B, B, 0, stream>>>(dst32, deg);
    k_dinv     <<<(N_NODES + B - 1) / B, B, 0, stream>>>(deg);

    k_gemm1<<<N_NODES / 8, B, 0, stream>>>(x, W1, deg, t1, a1);
    k_agg1 <<<(N_EDGES * 8) / B, B, 0, stream>>>(src32, dst32, deg, t1, a1);

    k_gemm2<<<N_NODES / 16, B, 0, stream>>>(a1, b1, W2, deg, t2, a2);
    k_agg2 <<<(N_EDGES * 4) / B, B, 0, stream>>>(src32, dst32, deg, t2, a2);

    k_final<<<(N_NODES + B - 1) / B, B, 0, stream>>>(a2, b2, Wc, bc, out);
}

// Round 4
// 694.979 us; speedup vs baseline: 3.2380x; 3.2380x over previous
//
#include <hip/hip_runtime.h>
#include <math.h>

#define N_NODES 100000
#define N_EDGES 3200000
#define D_FEAT 128
#define H1 32
#define H2 16
#define NC 8

// scan geometry: 98 blocks x 256 threads x 4 elems = 100352 >= 100001
#define SCAN_B 98
#define SCAN_T 256

// ---------------- edge-index dtype detect ----------------
// int64 little-endian with ids < 2^31 => every odd int32 word is 0.

__global__ void k_detect(const int* __restrict__ ei, int* __restrict__ meta) {
    __shared__ int red[256];
    int v = 0;
    for (int i = threadIdx.x; i < 1024; i += 256) v |= ei[2 * i + 1];
    red[threadIdx.x] = v;
    __syncthreads();
    for (int s = 128; s > 0; s >>= 1) {
        if (threadIdx.x < (unsigned)s) red[threadIdx.x] |= red[threadIdx.x + s];
        __syncthreads();
    }
    if (threadIdx.x == 0) meta[0] = (red[0] == 0) ? 1 : 0;  // 1 => int64
}

// ---------------- CSR build ----------------

__global__ void k_zero_cnt(int* __restrict__ cnt) {
    int v = blockIdx.x * blockDim.x + threadIdx.x;
    if (v < N_NODES) cnt[v] = 0;
}

__global__ void k_count(const int* __restrict__ ei, const int* __restrict__ meta,
                        int* __restrict__ cnt) {
    const int e = blockIdx.x * blockDim.x + threadIdx.x;
    if (e >= N_EDGES) return;
    const int d = meta[0] ? ei[2 * N_EDGES + 2 * e] : ei[N_EDGES + e];
    atomicAdd(&cnt[d], 1);
}

__global__ void k_dinv(const int* __restrict__ cnt, float* __restrict__ dinv) {
    int v = blockIdx.x * blockDim.x + threadIdx.x;
    if (v < N_NODES) dinv[v] = rsqrtf(1.0f + (float)cnt[v]);  // +1 self-loop
}

// scan phase 1: per-block sums of cnt
__global__ void k_scan1(const int* __restrict__ cnt, int* __restrict__ bsum) {
    __shared__ int sc[SCAN_T];
    const int tid = threadIdx.x;
    const int base = (blockIdx.x * SCAN_T + tid) * 4;
    int s = 0;
#pragma unroll
    for (int q = 0; q < 4; ++q) {
        const int i = base + q;
        if (i < N_NODES) s += cnt[i];
    }
    sc[tid] = s;
    __syncthreads();
    for (int st = SCAN_T / 2; st > 0; st >>= 1) {
        if (tid < st) sc[tid] += sc[tid + st];
        __syncthreads();
    }
    if (tid == 0) bsum[blockIdx.x] = sc[0];
}

// scan phase 2: serial exclusive scan of 98 block sums (thread 0)
__global__ void k_scan2(const int* __restrict__ bsum, int* __restrict__ boff) {
    if (threadIdx.x == 0) {
        int run = 0;
        for (int b = 0; b < SCAN_B; ++b) { boff[b] = run; run += bsum[b]; }
    }
}

// scan phase 3: element-wise exclusive prefix -> row_ptr, cursor
__global__ void k_scan3(const int* __restrict__ cnt, const int* __restrict__ boff,
                        int* __restrict__ row_ptr, int* __restrict__ cursor) {
    __shared__ int sc[SCAN_T];
    const int tid = threadIdx.x;
    const int base = (blockIdx.x * SCAN_T + tid) * 4;
    int c[4];
    int tot = 0;
#pragma unroll
    for (int q = 0; q < 4; ++q) {
        const int i = base + q;
        c[q] = (i < N_NODES) ? cnt[i] : 0;
        tot += c[q];
    }
    sc[tid] = tot;
    __syncthreads();
    // Hillis-Steele inclusive scan over 256 thread totals
    for (int off = 1; off < SCAN_T; off <<= 1) {
        const int vv = (tid >= off) ? sc[tid - off] : 0;
        __syncthreads();
        sc[tid] += vv;
        __syncthreads();
    }
    int run = boff[blockIdx.x] + sc[tid] - tot;  // exclusive offset for this thread
#pragma unroll
    for (int q = 0; q < 4; ++q) {
        const int i = base + q;
        if (i <= N_NODES) {
            row_ptr[i] = run;
            if (i < N_NODES) cursor[i] = run;
        }
        run += c[q];
    }
}

__global__ void k_fill(const int* __restrict__ ei, const int* __restrict__ meta,
                       int* __restrict__ cursor, int* __restrict__ col_idx) {
    const int e = blockIdx.x * blockDim.x + threadIdx.x;
    if (e >= N_EDGES) return;
    int s, d;
    if (meta[0]) { s = ei[2 * e]; d = ei[2 * N_EDGES + 2 * e]; }
    else         { s = ei[e];     d = ei[N_EDGES + e]; }
    const int slot = atomicAdd(&cursor[d], 1);
    col_idx[slot] = s;
}

// ---------------- layer 1 linear: u1 = dinv * (x @ W1) ----------------

__global__ __launch_bounds__(256) void k_gemm1(const float* __restrict__ x,
                                               const float* __restrict__ W1,
                                               const float* __restrict__ dinv,
                                               float* __restrict__ u1) {
    __shared__ float Ws[D_FEAT * H1];   // 16 KB
    __shared__ float xs[8][D_FEAT];     // 4 KB
    const int tid = threadIdx.x;
    for (int i = tid; i < D_FEAT * H1; i += 256) Ws[i] = W1[i];
    const int row0 = blockIdx.x * 8;    // 100000/8 = 12500 exact
    const float4* xg = (const float4*)(x + (size_t)row0 * D_FEAT);
    ((float4*)&xs[0][0])[tid] = xg[tid];
    __syncthreads();
    const int r = tid >> 5;   // 0..7
    const int j = tid & 31;   // 0..31
    float acc = 0.0f;
#pragma unroll 8
    for (int k = 0; k < D_FEAT; ++k)
        acc = fmaf(xs[r][k], Ws[k * H1 + j], acc);
    const int v = row0 + r;
    u1[(size_t)v * H1 + j] = acc * dinv[v];
}

// ---------------- pull aggregation, layer 1 (8 lanes/node, float4 each) -------
// a1[d] = dinv[d] * ( u1[d] + sum_{s in in(d)} u1[s] )

__global__ void k_pull1(const int* __restrict__ row_ptr, const int* __restrict__ col_idx,
                        const float* __restrict__ dinv,
                        const float* __restrict__ u1, float* __restrict__ a1) {
    const int t = blockIdx.x * blockDim.x + threadIdx.x;
    const int v = t >> 3;
    const int l = t & 7;
    if (v >= N_NODES) return;
    const float4* base = (const float4*)u1;
    float4 acc = base[(size_t)v * 8 + l];   // self-loop term
    const int beg = row_ptr[v];
    const int end = row_ptr[v + 1];
    for (int i = beg; i < end; ++i) {
        const int s = col_idx[i];
        const float4 w = base[(size_t)s * 8 + l];
        acc.x += w.x; acc.y += w.y; acc.z += w.z; acc.w += w.w;
    }
    const float dv = dinv[v];
    float4 o; o.x = acc.x * dv; o.y = acc.y * dv; o.z = acc.z * dv; o.w = acc.w * dv;
    ((float4*)a1)[(size_t)v * 8 + l] = o;
}

// ---------------- layer 2 linear: u2 = dinv * (relu(a1+b1) @ W2) -------------

__global__ __launch_bounds__(256) void k_gemm2(const float* __restrict__ a1,
                                               const float* __restrict__ b1,
                                               const float* __restrict__ W2,
                                               const float* __restrict__ dinv,
                                               float* __restrict__ u2) {
    __shared__ float Ws[H1 * H2];   // 512 floats
    __shared__ float hs[16 * H1];   // 512 floats
    const int tid = threadIdx.x;
    for (int i = tid; i < H1 * H2; i += 256) Ws[i] = W2[i];  // strided loop (R3 fix)
    const int row0 = blockIdx.x * 16;   // 100000/16 = 6250 exact
    for (int i = tid; i < 16 * H1; i += 256) {
        const int col = i & (H1 - 1);
        hs[i] = fmaxf(a1[(size_t)row0 * H1 + i] + b1[col], 0.0f);
    }
    __syncthreads();
    const int r = tid >> 4;   // 0..15
    const int j = tid & 15;   // 0..15
    float acc = 0.0f;
#pragma unroll
    for (int k = 0; k < H1; ++k)
        acc = fmaf(hs[r * H1 + k], Ws[k * H2 + j], acc);
    const int v = row0 + r;
    u2[(size_t)v * H2 + j] = acc * dinv[v];
}

// ---------------- pull aggregation, layer 2 (4 lanes/node) -------------------

__global__ void k_pull2(const int* __restrict__ row_ptr, const int* __restrict__ col_idx,
                        const float* __restrict__ dinv,
                        const float* __restrict__ u2, float* __restrict__ a2) {
    const int t = blockIdx.x * blockDim.x + threadIdx.x;
    const int v = t >> 2;
    const int l = t & 3;
    if (v >= N_NODES) return;
    const float4* base = (const float4*)u2;
    float4 acc = base[(size_t)v * 4 + l];   // self-loop term
    const int beg = row_ptr[v];
    const int end = row_ptr[v + 1];
    for (int i = beg; i < end; ++i) {
        const int s = col_idx[i];
        const float4 w = base[(size_t)s * 4 + l];
        acc.x += w.x; acc.y += w.y; acc.z += w.z; acc.w += w.w;
    }
    const float dv = dinv[v];
    float4 o; o.x = acc.x * dv; o.y = acc.y * dv; o.z = acc.z * dv; o.w = acc.w * dv;
    ((float4*)a2)[(size_t)v * 4 + l] = o;
}

// ---------------- final: relu(a2+b2) @ Wc + bc -> log_softmax ----------------

__global__ void k_final(const float* __restrict__ a2, const float* __restrict__ b2,
                        const float* __restrict__ Wc, const float* __restrict__ bc,
                        float* __restrict__ out) {
    const int v = blockIdx.x * blockDim.x + threadIdx.x;
    if (v >= N_NODES) return;
    float h[H2];
    const float4* ap = (const float4*)(a2 + (size_t)v * H2);
#pragma unroll
    for (int q = 0; q < 4; ++q) {
        const float4 p = ap[q];
        h[q * 4 + 0] = fmaxf(p.x + b2[q * 4 + 0], 0.0f);
        h[q * 4 + 1] = fmaxf(p.y + b2[q * 4 + 1], 0.0f);
        h[q * 4 + 2] = fmaxf(p.z + b2[q * 4 + 2], 0.0f);
        h[q * 4 + 3] = fmaxf(p.w + b2[q * 4 + 3], 0.0f);
    }
    float lg[NC];
#pragma unroll
    for (int j = 0; j < NC; ++j) lg[j] = bc[j];
#pragma unroll
    for (int k = 0; k < H2; ++k) {
        const float hk = h[k];
#pragma unroll
        for (int j = 0; j < NC; ++j)
            lg[j] = fmaf(hk, Wc[k * NC + j], lg[j]);
    }
    float m = lg[0];
#pragma unroll
    for (int j = 1; j < NC; ++j) m = fmaxf(m, lg[j]);
    float s = 0.0f;
#pragma unroll
    for (int j = 0; j < NC; ++j) s += expf(lg[j] - m);
    const float lse = logf(s);
    float4 o0, o1;
    o0.x = lg[0] - m - lse; o0.y = lg[1] - m - lse;
    o0.z = lg[2] - m - lse; o0.w = lg[3] - m - lse;
    o1.x = lg[4] - m - lse; o1.y = lg[5] - m - lse;
    o1.z = lg[6] - m - lse; o1.w = lg[7] - m - lse;
    float4* op = (float4*)(out + (size_t)v * NC);
    op[0] = o0; op[1] = o1;
}

// ---------------- host launch ----------------

extern "C" void kernel_launch(void* const* d_in, const int* in_sizes, int n_in,
                              void* d_out, int out_size, void* d_ws, size_t ws_size,
                              hipStream_t stream) {
    const float* x   = (const float*)d_in[0];
    const int*   ei  = (const int*)d_in[1];     // [2,E]; int64 or int32 (detected)
    const float* W1  = (const float*)d_in[2];
    const float* b1  = (const float*)d_in[3];
    const float* W2  = (const float*)d_in[4];
    const float* b2  = (const float*)d_in[5];
    const float* Wc  = (const float*)d_in[6];
    const float* bc  = (const float*)d_in[7];
    float* out = (float*)d_out;

    // workspace layout (4-byte units; ~46 MB total, < prior 58 MB footprint):
    int*   meta    = (int*)d_ws;            // 16
    int*   cnt     = meta + 16;             // 100000
    int*   row_ptr = cnt + 100000;          // 100016 (100001 used)
    int*   cursor  = row_ptr + 100016;      // 100000
    int*   bsum    = cursor + 100000;       // 128
    int*   boff    = bsum + 128;            // 128
    int*   col_idx = boff + 128;            // 3200000
    float* dinv    = (float*)(col_idx + N_EDGES);        // 100000
    float* u1      = dinv + 100000;                      // 3200000
    float* a1      = u1 + (size_t)N_NODES * H1;          // 3200000
    float* u2      = a1 + (size_t)N_NODES * H1;          // 1600000
    float* a2      = u1;   // u1 dead after k_pull1; k_gemm2 reads only a1

    const int B = 256;
    k_detect  <<<1, B, 0, stream>>>(ei, meta);
    k_zero_cnt<<<(N_NODES + B - 1) / B, B, 0, stream>>>(cnt);
    k_count   <<<(N_EDGES + B - 1) / B, B, 0, stream>>>(ei, meta, cnt);
    k_dinv    <<<(N_NODES + B - 1) / B, B, 0, stream>>>(cnt, dinv);
    k_scan1   <<<SCAN_B, SCAN_T, 0, stream>>>(cnt, bsum);
    k_scan2   <<<1, 64, 0, stream>>>(bsum, boff);
    k_scan3   <<<SCAN_B, SCAN_T, 0, stream>>>(cnt, boff, row_ptr, cursor);
    k_fill    <<<(N_EDGES + B - 1) / B, B, 0, stream>>>(ei, meta, cursor, col_idx);

    k_gemm1<<<N_NODES / 8, B, 0, stream>>>(x, W1, dinv, u1);
    k_pull1<<<(N_NODES * 8) / B, B, 0, stream>>>(row_ptr, col_idx, dinv, u1, a1);

    k_gemm2<<<N_NODES / 16, B, 0, stream>>>(a1, b1, W2, dinv, u2);
    k_pull2<<<(N_NODES * 4 + B - 1) / B, B, 0, stream>>>(row_ptr, col_idx, dinv, u2, a2);

    k_final<<<(N_NODES + B - 1) / B, B, 0, stream>>>(a2, b2, Wc, bc, out);
}

// Round 5
// 508.408 us; speedup vs baseline: 4.4262x; 1.3670x over previous
//
#include <hip/hip_runtime.h>
#include <math.h>

#define N_NODES 100000
#define N_EDGES 3200000
#define D_FEAT 128
#define H1 32
#define H2 16
#define NC 8

#define NBUCK 391          // buckets of 256 dst nodes: ceil(100000/256)
#define EPB 8192           // edges per k_bscatter block
#define SCAN_B 98          // row_ptr scan geometry: 98*256*4 >= 100001
#define SCAN_T 256

// ---------------- edge-index dtype detect ----------------
// int64 little-endian with ids < 2^31 => every odd int32 word is 0.

__global__ void k_detect(const int* __restrict__ ei, int* __restrict__ meta) {
    __shared__ int red[256];
    int v = 0;
    for (int i = threadIdx.x; i < 1024; i += 256) v |= ei[2 * i + 1];
    red[threadIdx.x] = v;
    __syncthreads();
    for (int s = 128; s > 0; s >>= 1) {
        if (threadIdx.x < (unsigned)s) red[threadIdx.x] |= red[threadIdx.x + s];
        __syncthreads();
    }
    if (threadIdx.x == 0) meta[0] = (red[0] == 0) ? 1 : 0;  // 1 => int64
}

__global__ void k_zero(int* __restrict__ cnt, int* __restrict__ bucket_cnt) {
    const int v = blockIdx.x * blockDim.x + threadIdx.x;
    if (v < N_NODES) cnt[v] = 0;
    if (v < NBUCK) bucket_cnt[v] = 0;
}

// ---------------- pass A: per-node degree + per-bucket histogram ----------------

__global__ __launch_bounds__(256) void k_hist(const int* __restrict__ ei,
                                              const int* __restrict__ meta,
                                              int* __restrict__ cnt,
                                              int* __restrict__ bucket_cnt) {
    __shared__ int bh[NBUCK];
    const int tid = threadIdx.x;
    for (int i = tid; i < NBUCK; i += 256) bh[i] = 0;
    __syncthreads();
    const bool is64 = (meta[0] != 0);
    const int stride = gridDim.x * blockDim.x;
    for (int e = blockIdx.x * blockDim.x + tid; e < N_EDGES; e += stride) {
        const int d = is64 ? ei[2 * N_EDGES + 2 * e] : ei[N_EDGES + e];
        atomicAdd(&cnt[d], 1);
        atomicAdd(&bh[d >> 8], 1);
    }
    __syncthreads();
    for (int i = tid; i < NBUCK; i += 256)
        if (bh[i]) atomicAdd(&bucket_cnt[i], bh[i]);
}

__global__ void k_dinv(const int* __restrict__ cnt, float* __restrict__ dinv) {
    const int v = blockIdx.x * blockDim.x + threadIdx.x;
    if (v < N_NODES) dinv[v] = rsqrtf(1.0f + (float)cnt[v]);  // +1 self-loop
}

// ---------------- row_ptr scan (3 phases, as R4) ----------------

__global__ void k_scan1(const int* __restrict__ cnt, int* __restrict__ bsum) {
    __shared__ int sc[SCAN_T];
    const int tid = threadIdx.x;
    const int base = (blockIdx.x * SCAN_T + tid) * 4;
    int s = 0;
#pragma unroll
    for (int q = 0; q < 4; ++q) {
        const int i = base + q;
        if (i < N_NODES) s += cnt[i];
    }
    sc[tid] = s;
    __syncthreads();
    for (int st = SCAN_T / 2; st > 0; st >>= 1) {
        if (tid < st) sc[tid] += sc[tid + st];
        __syncthreads();
    }
    if (tid == 0) bsum[blockIdx.x] = sc[0];
}

__global__ void k_scan2(const int* __restrict__ bsum, int* __restrict__ boff) {
    if (threadIdx.x == 0) {
        int run = 0;
        for (int b = 0; b < SCAN_B; ++b) { boff[b] = run; run += bsum[b]; }
    }
}

__global__ void k_scan3(const int* __restrict__ cnt, const int* __restrict__ boff,
                        int* __restrict__ row_ptr) {
    __shared__ int sc[SCAN_T];
    const int tid = threadIdx.x;
    const int base = (blockIdx.x * SCAN_T + tid) * 4;
    int c[4];
    int tot = 0;
#pragma unroll
    for (int q = 0; q < 4; ++q) {
        const int i = base + q;
        c[q] = (i < N_NODES) ? cnt[i] : 0;
        tot += c[q];
    }
    sc[tid] = tot;
    __syncthreads();
    for (int off = 1; off < SCAN_T; off <<= 1) {
        const int vv = (tid >= off) ? sc[tid - off] : 0;
        __syncthreads();
        sc[tid] += vv;
        __syncthreads();
    }
    int run = boff[blockIdx.x] + sc[tid] - tot;  // exclusive offset
#pragma unroll
    for (int q = 0; q < 4; ++q) {
        const int i = base + q;
        if (i <= N_NODES) row_ptr[i] = run;
        run += c[q];
    }
}

// ---------------- bucket scan ----------------

__global__ __launch_bounds__(512) void k_bscan(const int* __restrict__ bucket_cnt,
                                               int* __restrict__ bucket_base,
                                               int* __restrict__ bucket_cursor) {
    __shared__ int h[512];
    const int tid = threadIdx.x;
    const int own = (tid < NBUCK) ? bucket_cnt[tid] : 0;
    h[tid] = own;
    __syncthreads();
    for (int off = 1; off < 512; off <<= 1) {
        const int v = (tid >= off) ? h[tid - off] : 0;
        __syncthreads();
        h[tid] += v;
        __syncthreads();
    }
    const int incl = h[tid];
    if (tid < NBUCK) {
        bucket_base[tid] = incl - own;
        bucket_cursor[tid] = incl - own;
        if (tid == NBUCK - 1) bucket_base[NBUCK] = incl;  // == N_EDGES
    }
}

// ---------------- pass C: bucket-grouped edge scatter ----------------
// Per-(block,bucket) exclusive output segments -> one writer per cache line
// (modulo segment-boundary lines) -> L2 merges -> ~1x HBM write amplification.

__global__ __launch_bounds__(512) void k_bscatter(const int* __restrict__ ei,
                                                  const int* __restrict__ meta,
                                                  int* __restrict__ bucket_cursor,
                                                  int2* __restrict__ ebuf) {
    __shared__ int h[512];
    __shared__ int lo[512];
    __shared__ int gb[512];
    __shared__ int rank[512];
    const int tid = threadIdx.x;
    h[tid] = 0; rank[tid] = 0;
    __syncthreads();
    const int e0 = blockIdx.x * EPB;
    const int n = min(EPB, N_EDGES - e0);
    const bool is64 = (meta[0] != 0);
    for (int i = tid; i < n; i += 512) {
        const int e = e0 + i;
        const int d = is64 ? ei[2 * N_EDGES + 2 * e] : ei[N_EDGES + e];
        atomicAdd(&h[d >> 8], 1);
    }
    __syncthreads();
    const int own = h[tid];
    for (int off = 1; off < 512; off <<= 1) {
        const int v = (tid >= off) ? h[tid - off] : 0;
        __syncthreads();
        h[tid] += v;
        __syncthreads();
    }
    lo[tid] = h[tid] - own;  // exclusive (unused for math, kept for clarity/debug)
    if (tid < NBUCK && own > 0) gb[tid] = atomicAdd(&bucket_cursor[tid], own);
    __syncthreads();
    for (int i = tid; i < n; i += 512) {
        const int e = e0 + i;
        int s, d;
        if (is64) { s = ei[2 * e]; d = ei[2 * N_EDGES + 2 * e]; }
        else      { s = ei[e];     d = ei[N_EDGES + e]; }
        const int b = d >> 8;
        const int r = atomicAdd(&rank[b], 1);
        ebuf[gb[b] + r] = make_int2(s, d);
    }
}

// ---------------- pass D: CSR col_idx fill (one block per bucket) ----------------
// Each block owns a contiguous ~33KB col_idx window -> XCD-local L2 merging.

__global__ __launch_bounds__(256) void k_bfill(const int2* __restrict__ ebuf,
                                               const int* __restrict__ bucket_base,
                                               const int* __restrict__ row_ptr,
                                               int* __restrict__ col_idx) {
    __shared__ int cur[256];
    const int b = blockIdx.x;
    const int tid = threadIdx.x;
    const int v = (b << 8) + tid;
    if (v < N_NODES) cur[tid] = row_ptr[v];
    __syncthreads();
    const int eb = bucket_base[b], ee = bucket_base[b + 1];
    for (int i = eb + tid; i < ee; i += 256) {
        const int2 pr = ebuf[i];
        const int slot = atomicAdd(&cur[pr.y & 255], 1);
        col_idx[slot] = pr.x;
    }
}

// ---------------- layer 1 linear: u1 = dinv * (x @ W1) ----------------

__global__ __launch_bounds__(256) void k_gemm1(const float* __restrict__ x,
                                               const float* __restrict__ W1,
                                               const float* __restrict__ dinv,
                                               float* __restrict__ u1) {
    __shared__ float Ws[D_FEAT * H1];   // 16 KB
    __shared__ float xs[8][D_FEAT];     // 4 KB
    const int tid = threadIdx.x;
    for (int i = tid; i < D_FEAT * H1; i += 256) Ws[i] = W1[i];
    const int row0 = blockIdx.x * 8;    // 100000/8 = 12500 exact
    const float4* xg = (const float4*)(x + (size_t)row0 * D_FEAT);
    ((float4*)&xs[0][0])[tid] = xg[tid];
    __syncthreads();
    const int r = tid >> 5;
    const int j = tid & 31;
    float acc = 0.0f;
#pragma unroll 8
    for (int k = 0; k < D_FEAT; ++k)
        acc = fmaf(xs[r][k], Ws[k * H1 + j], acc);
    const int v = row0 + r;
    u1[(size_t)v * H1 + j] = acc * dinv[v];
}

// ---------------- pull aggregation, layer 1 (8 lanes/node, float4 each) -------

__global__ void k_pull1(const int* __restrict__ row_ptr, const int* __restrict__ col_idx,
                        const float* __restrict__ dinv,
                        const float* __restrict__ u1, float* __restrict__ a1) {
    const int t = blockIdx.x * blockDim.x + threadIdx.x;
    const int v = t >> 3;
    const int l = t & 7;
    if (v >= N_NODES) return;
    const float4* base = (const float4*)u1;
    float4 acc = base[(size_t)v * 8 + l];   // self-loop term
    const int beg = row_ptr[v];
    const int end = row_ptr[v + 1];
    for (int i = beg; i < end; ++i) {
        const int s = col_idx[i];
        const float4 w = base[(size_t)s * 8 + l];
        acc.x += w.x; acc.y += w.y; acc.z += w.z; acc.w += w.w;
    }
    const float dv = dinv[v];
    float4 o; o.x = acc.x * dv; o.y = acc.y * dv; o.z = acc.z * dv; o.w = acc.w * dv;
    ((float4*)a1)[(size_t)v * 8 + l] = o;
}

// ---------------- layer 2 linear: u2 = dinv * (relu(a1+b1) @ W2) -------------

__global__ __launch_bounds__(256) void k_gemm2(const float* __restrict__ a1,
                                               const float* __restrict__ b1,
                                               const float* __restrict__ W2,
                                               const float* __restrict__ dinv,
                                               float* __restrict__ u2) {
    __shared__ float Ws[H1 * H2];
    __shared__ float hs[16 * H1];
    const int tid = threadIdx.x;
    for (int i = tid; i < H1 * H2; i += 256) Ws[i] = W2[i];
    const int row0 = blockIdx.x * 16;   // 100000/16 = 6250 exact
    for (int i = tid; i < 16 * H1; i += 256) {
        const int col = i & (H1 - 1);
        hs[i] = fmaxf(a1[(size_t)row0 * H1 + i] + b1[col], 0.0f);
    }
    __syncthreads();
    const int r = tid >> 4;
    const int j = tid & 15;
    float acc = 0.0f;
#pragma unroll
    for (int k = 0; k < H1; ++k)
        acc = fmaf(hs[r * H1 + k], Ws[k * H2 + j], acc);
    const int v = row0 + r;
    u2[(size_t)v * H2 + j] = acc * dinv[v];
}

// ---------------- pull aggregation, layer 2 (4 lanes/node) -------------------

__global__ void k_pull2(const int* __restrict__ row_ptr, const int* __restrict__ col_idx,
                        const float* __restrict__ dinv,
                        const float* __restrict__ u2, float* __restrict__ a2) {
    const int t = blockIdx.x * blockDim.x + threadIdx.x;
    const int v = t >> 2;
    const int l = t & 3;
    if (v >= N_NODES) return;
    const float4* base = (const float4*)u2;
    float4 acc = base[(size_t)v * 4 + l];   // self-loop term
    const int beg = row_ptr[v];
    const int end = row_ptr[v + 1];
    for (int i = beg; i < end; ++i) {
        const int s = col_idx[i];
        const float4 w = base[(size_t)s * 4 + l];
        acc.x += w.x; acc.y += w.y; acc.z += w.z; acc.w += w.w;
    }
    const float dv = dinv[v];
    float4 o; o.x = acc.x * dv; o.y = acc.y * dv; o.z = acc.z * dv; o.w = acc.w * dv;
    ((float4*)a2)[(size_t)v * 4 + l] = o;
}

// ---------------- final: relu(a2+b2) @ Wc + bc -> log_softmax ----------------

__global__ void k_final(const float* __restrict__ a2, const float* __restrict__ b2,
                        const float* __restrict__ Wc, const float* __restrict__ bc,
                        float* __restrict__ out) {
    const int v = blockIdx.x * blockDim.x + threadIdx.x;
    if (v >= N_NODES) return;
    float h[H2];
    const float4* ap = (const float4*)(a2 + (size_t)v * H2);
#pragma unroll
    for (int q = 0; q < 4; ++q) {
        const float4 p = ap[q];
        h[q * 4 + 0] = fmaxf(p.x + b2[q * 4 + 0], 0.0f);
        h[q * 4 + 1] = fmaxf(p.y + b2[q * 4 + 1], 0.0f);
        h[q * 4 + 2] = fmaxf(p.z + b2[q * 4 + 2], 0.0f);
        h[q * 4 + 3] = fmaxf(p.w + b2[q * 4 + 3], 0.0f);
    }
    float lg[NC];
#pragma unroll
    for (int j = 0; j < NC; ++j) lg[j] = bc[j];
#pragma unroll
    for (int k = 0; k < H2; ++k) {
        const float hk = h[k];
#pragma unroll
        for (int j = 0; j < NC; ++j)
            lg[j] = fmaf(hk, Wc[k * NC + j], lg[j]);
    }
    float m = lg[0];
#pragma unroll
    for (int j = 1; j < NC; ++j) m = fmaxf(m, lg[j]);
    float s = 0.0f;
#pragma unroll
    for (int j = 0; j < NC; ++j) s += expf(lg[j] - m);
    const float lse = logf(s);
    float4 o0, o1;
    o0.x = lg[0] - m - lse; o0.y = lg[1] - m - lse;
    o0.z = lg[2] - m - lse; o0.w = lg[3] - m - lse;
    o1.x = lg[4] - m - lse; o1.y = lg[5] - m - lse;
    o1.z = lg[6] - m - lse; o1.w = lg[7] - m - lse;
    float4* op = (float4*)(out + (size_t)v * NC);
    op[0] = o0; op[1] = o1;
}

// ---------------- host launch ----------------

extern "C" void kernel_launch(void* const* d_in, const int* in_sizes, int n_in,
                              void* d_out, int out_size, void* d_ws, size_t ws_size,
                              hipStream_t stream) {
    const float* x   = (const float*)d_in[0];
    const int*   ei  = (const int*)d_in[1];
    const float* W1  = (const float*)d_in[2];
    const float* b1  = (const float*)d_in[3];
    const float* W2  = (const float*)d_in[4];
    const float* b2  = (const float*)d_in[5];
    const float* Wc  = (const float*)d_in[6];
    const float* bc  = (const float*)d_in[7];
    float* out = (float*)d_out;

    // workspace layout (int units). Total ~46 MB.
    int*   meta          = (int*)d_ws;                   // 16
    int*   cnt           = meta + 16;                    // 100000
    int*   row_ptr       = cnt + 100000;                 // 100016 (100001 used)
    int*   bsum          = row_ptr + 100016;             // 128
    int*   boff          = bsum + 128;                   // 128
    int*   bucket_cnt    = boff + 128;                   // 512
    int*   bucket_base   = bucket_cnt + 512;             // 512 (NBUCK+1 used)
    int*   bucket_cursor = bucket_base + 512;            // 512
    float* dinv          = (float*)(bucket_cursor + 512);// 100000
    int*   col_idx       = (int*)(dinv + 100000);        // 3200000
    int*   ebuf_i        = col_idx + 3200000;            // 6400000 (int2 x 3.2M), 8B-aligned
    int2*  ebuf          = (int2*)ebuf_i;
    // feature buffers alias ebuf (dead after k_bfill):
    float* u1 = (float*)ebuf_i;                          // 3200000
    float* a1 = u1 + (size_t)N_NODES * H1;               // 3200000
    float* u2 = a1 + (size_t)N_NODES * H1;               // 1600000 (beyond ebuf)
    float* a2 = u1;                                      // u1 dead after k_pull1

    const int B = 256;
    k_detect  <<<1, B, 0, stream>>>(ei, meta);
    k_zero    <<<(N_NODES + B - 1) / B, B, 0, stream>>>(cnt, bucket_cnt);
    k_hist    <<<1024, B, 0, stream>>>(ei, meta, cnt, bucket_cnt);
    k_dinv    <<<(N_NODES + B - 1) / B, B, 0, stream>>>(cnt, dinv);
    k_scan1   <<<SCAN_B, SCAN_T, 0, stream>>>(cnt, bsum);
    k_scan2   <<<1, 64, 0, stream>>>(bsum, boff);
    k_scan3   <<<SCAN_B, SCAN_T, 0, stream>>>(cnt, boff, row_ptr);
    k_bscan   <<<1, 512, 0, stream>>>(bucket_cnt, bucket_base, bucket_cursor);
    k_bscatter<<<(N_EDGES + EPB - 1) / EPB, 512, 0, stream>>>(ei, meta, bucket_cursor, ebuf);
    k_bfill   <<<NBUCK, B, 0, stream>>>(ebuf, bucket_base, row_ptr, col_idx);

    k_gemm1<<<N_NODES / 8, B, 0, stream>>>(x, W1, dinv, u1);
    k_pull1<<<(N_NODES * 8) / B, B, 0, stream>>>(row_ptr, col_idx, dinv, u1, a1);

    k_gemm2<<<N_NODES / 16, B, 0, stream>>>(a1, b1, W2, dinv, u2);
    k_pull2<<<(N_NODES * 4 + B - 1) / B, B, 0, stream>>>(row_ptr, col_idx, dinv, u2, a2);

    k_final<<<(N_NODES + B - 1) / B, B, 0, stream>>>(a2, b2, Wc, bc, out);
}

// Round 6
// 376.966 us; speedup vs baseline: 5.9696x; 1.3487x over previous
//
#include <hip/hip_runtime.h>
#include <math.h>

#define N_NODES 100000
#define N_EDGES 3200000
#define D_FEAT 128
#define H1 32
#define H2 16
#define NC 8

#define NBUCK 391          // buckets of 256 dst nodes: ceil(100000/256)
#define EPB 8192           // edges per k_bscatter block

// ---------------- detect edge dtype + zero bucket counters ----------------
// int64 little-endian with ids < 2^31 => every odd int32 word is 0.

__global__ void k_detect(const int* __restrict__ ei, int* __restrict__ meta,
                         int* __restrict__ bucket_cnt) {
    __shared__ int red[256];
    int v = 0;
    for (int i = threadIdx.x; i < 1024; i += 256) v |= ei[2 * i + 1];
    red[threadIdx.x] = v;
    __syncthreads();
    for (int s = 128; s > 0; s >>= 1) {
        if (threadIdx.x < (unsigned)s) red[threadIdx.x] |= red[threadIdx.x + s];
        __syncthreads();
    }
    if (threadIdx.x == 0) meta[0] = (red[0] == 0) ? 1 : 0;  // 1 => int64
    for (int i = threadIdx.x; i < NBUCK; i += 256) bucket_cnt[i] = 0;
}

// ---------------- pass A: per-bucket histogram ONLY (LDS; no per-node atomics) --

__global__ __launch_bounds__(256) void k_hist(const int* __restrict__ ei,
                                              const int* __restrict__ meta,
                                              int* __restrict__ bucket_cnt) {
    __shared__ int bh[NBUCK];
    const int tid = threadIdx.x;
    for (int i = tid; i < NBUCK; i += 256) bh[i] = 0;
    __syncthreads();
    const bool is64 = (meta[0] != 0);
    const int stride = gridDim.x * blockDim.x;
    for (int e = blockIdx.x * blockDim.x + tid; e < N_EDGES; e += stride) {
        const int d = is64 ? ei[2 * N_EDGES + 2 * e] : ei[N_EDGES + e];
        atomicAdd(&bh[d >> 8], 1);
    }
    __syncthreads();
    for (int i = tid; i < NBUCK; i += 256)
        if (bh[i]) atomicAdd(&bucket_cnt[i], bh[i]);
}

// ---------------- bucket scan ----------------

__global__ __launch_bounds__(512) void k_bscan(const int* __restrict__ bucket_cnt,
                                               int* __restrict__ bucket_base,
                                               int* __restrict__ bucket_cursor) {
    __shared__ int h[512];
    const int tid = threadIdx.x;
    const int own = (tid < NBUCK) ? bucket_cnt[tid] : 0;
    h[tid] = own;
    __syncthreads();
    for (int off = 1; off < 512; off <<= 1) {
        const int v = (tid >= off) ? h[tid - off] : 0;
        __syncthreads();
        h[tid] += v;
        __syncthreads();
    }
    const int incl = h[tid];
    if (tid < NBUCK) {
        bucket_base[tid] = incl - own;
        bucket_cursor[tid] = incl - own;
        if (tid == NBUCK - 1) bucket_base[NBUCK] = incl;  // == N_EDGES
    }
}

// ---------------- pass B: bucket-grouped edge scatter ----------------
// Per-(block,bucket) exclusive output segments -> one writer per cache line.

__global__ __launch_bounds__(512) void k_bscatter(const int* __restrict__ ei,
                                                  const int* __restrict__ meta,
                                                  int* __restrict__ bucket_cursor,
                                                  int2* __restrict__ ebuf) {
    __shared__ int h[512];
    __shared__ int gb[512];
    __shared__ int rank[512];
    const int tid = threadIdx.x;
    h[tid] = 0; rank[tid] = 0;
    __syncthreads();
    const int e0 = blockIdx.x * EPB;
    const int n = min(EPB, N_EDGES - e0);
    const bool is64 = (meta[0] != 0);
    for (int i = tid; i < n; i += 512) {
        const int e = e0 + i;
        const int d = is64 ? ei[2 * N_EDGES + 2 * e] : ei[N_EDGES + e];
        atomicAdd(&h[d >> 8], 1);
    }
    __syncthreads();
    const int own = h[tid];
    if (tid < NBUCK && own > 0) gb[tid] = atomicAdd(&bucket_cursor[tid], own);
    __syncthreads();
    for (int i = tid; i < n; i += 512) {
        const int e = e0 + i;
        int s, d;
        if (is64) { s = ei[2 * e]; d = ei[2 * N_EDGES + 2 * e]; }
        else      { s = ei[e];     d = ei[N_EDGES + e]; }
        const int b = d >> 8;
        const int r = atomicAdd(&rank[b], 1);
        ebuf[gb[b] + r] = make_int2(s, d);
    }
}

// ---------------- pass C: per-bucket degree+scan+fill (one block per bucket) ----
// Bucket b owns nodes [256b, 256b+256). Its ebuf segment holds exactly their
// in-edges, so row_ptr[v] = bucket_base[b] + local exclusive prefix — no global
// scan, no global per-node atomics. Also emits dinv and fills col_idx.

__global__ __launch_bounds__(256) void k_bfill2(const int2* __restrict__ ebuf,
                                                const int* __restrict__ bucket_base,
                                                int* __restrict__ row_ptr,
                                                float* __restrict__ dinv,
                                                int* __restrict__ col_idx) {
    __shared__ int cnt[256];
    __shared__ int sc[256];
    __shared__ int cur[256];
    const int b = blockIdx.x;
    const int tid = threadIdx.x;
    cnt[tid] = 0;
    __syncthreads();
    const int eb = bucket_base[b], ee = bucket_base[b + 1];
    for (int i = eb + tid; i < ee; i += 256)
        atomicAdd(&cnt[ebuf[i].y & 255], 1);
    __syncthreads();
    const int own = cnt[tid];
    sc[tid] = own;
    __syncthreads();
    for (int off = 1; off < 256; off <<= 1) {
        const int v = (tid >= off) ? sc[tid - off] : 0;
        __syncthreads();
        sc[tid] += v;
        __syncthreads();
    }
    const int excl = sc[tid] - own;
    const int v = (b << 8) + tid;
    if (v <= N_NODES) row_ptr[v] = eb + excl;   // v==N_NODES lands here (bucket 390, tid 160)
    if (v < N_NODES) dinv[v] = rsqrtf(1.0f + (float)own);  // +1 self-loop
    cur[tid] = eb + excl;
    __syncthreads();
    for (int i = eb + tid; i < ee; i += 256) {
        const int2 pr = ebuf[i];
        const int slot = atomicAdd(&cur[pr.y & 255], 1);
        col_idx[slot] = pr.x;
    }
}

// ---------------- layer 1 linear: u1 = dinv * (x @ W1) ----------------

__global__ __launch_bounds__(256) void k_gemm1(const float* __restrict__ x,
                                               const float* __restrict__ W1,
                                               const float* __restrict__ dinv,
                                               float* __restrict__ u1) {
    __shared__ float Ws[D_FEAT * H1];   // 16 KB
    __shared__ float xs[8][D_FEAT];     // 4 KB
    const int tid = threadIdx.x;
    for (int i = tid; i < D_FEAT * H1; i += 256) Ws[i] = W1[i];
    const int row0 = blockIdx.x * 8;    // 100000/8 = 12500 exact
    const float4* xg = (const float4*)(x + (size_t)row0 * D_FEAT);
    ((float4*)&xs[0][0])[tid] = xg[tid];
    __syncthreads();
    const int r = tid >> 5;
    const int j = tid & 31;
    float acc = 0.0f;
#pragma unroll 8
    for (int k = 0; k < D_FEAT; ++k)
        acc = fmaf(xs[r][k], Ws[k * H1 + j], acc);
    const int v = row0 + r;
    u1[(size_t)v * H1 + j] = acc * dinv[v];
}

// ---------------- pull aggregation, layer 1 (8 lanes/node, float4 each) -------

__global__ void k_pull1(const int* __restrict__ row_ptr, const int* __restrict__ col_idx,
                        const float* __restrict__ dinv,
                        const float* __restrict__ u1, float* __restrict__ a1) {
    const int t = blockIdx.x * blockDim.x + threadIdx.x;
    const int v = t >> 3;
    const int l = t & 7;
    if (v >= N_NODES) return;
    const float4* base = (const float4*)u1;
    float4 acc = base[(size_t)v * 8 + l];   // self-loop term
    const int beg = row_ptr[v];
    const int end = row_ptr[v + 1];
    for (int i = beg; i < end; ++i) {
        const int s = col_idx[i];
        const float4 w = base[(size_t)s * 8 + l];
        acc.x += w.x; acc.y += w.y; acc.z += w.z; acc.w += w.w;
    }
    const float dv = dinv[v];
    float4 o; o.x = acc.x * dv; o.y = acc.y * dv; o.z = acc.z * dv; o.w = acc.w * dv;
    ((float4*)a1)[(size_t)v * 8 + l] = o;
}

// ---------------- layer 2 linear: u2 = dinv * (relu(a1+b1) @ W2) -------------

__global__ __launch_bounds__(256) void k_gemm2(const float* __restrict__ a1,
                                               const float* __restrict__ b1,
                                               const float* __restrict__ W2,
                                               const float* __restrict__ dinv,
                                               float* __restrict__ u2) {
    __shared__ float Ws[H1 * H2];
    __shared__ float hs[16 * H1];
    const int tid = threadIdx.x;
    for (int i = tid; i < H1 * H2; i += 256) Ws[i] = W2[i];
    const int row0 = blockIdx.x * 16;   // 100000/16 = 6250 exact
    for (int i = tid; i < 16 * H1; i += 256) {
        const int col = i & (H1 - 1);
        hs[i] = fmaxf(a1[(size_t)row0 * H1 + i] + b1[col], 0.0f);
    }
    __syncthreads();
    const int r = tid >> 4;
    const int j = tid & 15;
    float acc = 0.0f;
#pragma unroll
    for (int k = 0; k < H1; ++k)
        acc = fmaf(hs[r * H1 + k], Ws[k * H2 + j], acc);
    const int v = row0 + r;
    u2[(size_t)v * H2 + j] = acc * dinv[v];
}

// ---------------- pull aggregation, layer 2 (4 lanes/node) -------------------

__global__ void k_pull2(const int* __restrict__ row_ptr, const int* __restrict__ col_idx,
                        const float* __restrict__ dinv,
                        const float* __restrict__ u2, float* __restrict__ a2) {
    const int t = blockIdx.x * blockDim.x + threadIdx.x;
    const int v = t >> 2;
    const int l = t & 3;
    if (v >= N_NODES) return;
    const float4* base = (const float4*)u2;
    float4 acc = base[(size_t)v * 4 + l];   // self-loop term
    const int beg = row_ptr[v];
    const int end = row_ptr[v + 1];
    for (int i = beg; i < end; ++i) {
        const int s = col_idx[i];
        const float4 w = base[(size_t)s * 4 + l];
        acc.x += w.x; acc.y += w.y; acc.z += w.z; acc.w += w.w;
    }
    const float dv = dinv[v];
    float4 o; o.x = acc.x * dv; o.y = acc.y * dv; o.z = acc.z * dv; o.w = acc.w * dv;
    ((float4*)a2)[(size_t)v * 4 + l] = o;
}

// ---------------- final: relu(a2+b2) @ Wc + bc -> log_softmax ----------------

__global__ void k_final(const float* __restrict__ a2, const float* __restrict__ b2,
                        const float* __restrict__ Wc, const float* __restrict__ bc,
                        float* __restrict__ out) {
    const int v = blockIdx.x * blockDim.x + threadIdx.x;
    if (v >= N_NODES) return;
    float h[H2];
    const float4* ap = (const float4*)(a2 + (size_t)v * H2);
#pragma unroll
    for (int q = 0; q < 4; ++q) {
        const float4 p = ap[q];
        h[q * 4 + 0] = fmaxf(p.x + b2[q * 4 + 0], 0.0f);
        h[q * 4 + 1] = fmaxf(p.y + b2[q * 4 + 1], 0.0f);
        h[q * 4 + 2] = fmaxf(p.z + b2[q * 4 + 2], 0.0f);
        h[q * 4 + 3] = fmaxf(p.w + b2[q * 4 + 3], 0.0f);
    }
    float lg[NC];
#pragma unroll
    for (int j = 0; j < NC; ++j) lg[j] = bc[j];
#pragma unroll
    for (int k = 0; k < H2; ++k) {
        const float hk = h[k];
#pragma unroll
        for (int j = 0; j < NC; ++j)
            lg[j] = fmaf(hk, Wc[k * NC + j], lg[j]);
    }
    float m = lg[0];
#pragma unroll
    for (int j = 1; j < NC; ++j) m = fmaxf(m, lg[j]);
    float s = 0.0f;
#pragma unroll
    for (int j = 0; j < NC; ++j) s += expf(lg[j] - m);
    const float lse = logf(s);
    float4 o0, o1;
    o0.x = lg[0] - m - lse; o0.y = lg[1] - m - lse;
    o0.z = lg[2] - m - lse; o0.w = lg[3] - m - lse;
    o1.x = lg[4] - m - lse; o1.y = lg[5] - m - lse;
    o1.z = lg[6] - m - lse; o1.w = lg[7] - m - lse;
    float4* op = (float4*)(out + (size_t)v * NC);
    op[0] = o0; op[1] = o1;
}

// ---------------- host launch ----------------

extern "C" void kernel_launch(void* const* d_in, const int* in_sizes, int n_in,
                              void* d_out, int out_size, void* d_ws, size_t ws_size,
                              hipStream_t stream) {
    const float* x   = (const float*)d_in[0];
    const int*   ei  = (const int*)d_in[1];
    const float* W1  = (const float*)d_in[2];
    const float* b1  = (const float*)d_in[3];
    const float* W2  = (const float*)d_in[4];
    const float* b2  = (const float*)d_in[5];
    const float* Wc  = (const float*)d_in[6];
    const float* bc  = (const float*)d_in[7];
    float* out = (float*)d_out;

    // workspace layout (int units). ~45 MB total.
    int*   meta          = (int*)d_ws;                   // 16
    int*   bucket_cnt    = meta + 16;                    // 512
    int*   bucket_base   = bucket_cnt + 512;             // 512 (NBUCK+1 used)
    int*   bucket_cursor = bucket_base + 512;            // 512
    int*   row_ptr       = bucket_cursor + 512;          // 100016 (100001 used)
    float* dinv          = (float*)(row_ptr + 100016);   // 100000
    int*   col_idx       = (int*)(dinv + 100000);        // 3200000
    int*   ebuf_i        = col_idx + 3200000;            // 6400000 (int2 x 3.2M), 8B-aligned
    int2*  ebuf          = (int2*)ebuf_i;
    // feature buffers alias ebuf (dead after k_bfill2):
    float* u1 = (float*)ebuf_i;                          // 3200000
    float* a1 = u1 + (size_t)N_NODES * H1;               // 3200000
    float* u2 = a1 + (size_t)N_NODES * H1;               // 1600000 (beyond ebuf)
    float* a2 = u1;                                      // u1 dead after k_pull1

    const int B = 256;
    k_detect  <<<1, B, 0, stream>>>(ei, meta, bucket_cnt);
    k_hist    <<<1024, B, 0, stream>>>(ei, meta, bucket_cnt);
    k_bscan   <<<1, 512, 0, stream>>>(bucket_cnt, bucket_base, bucket_cursor);
    k_bscatter<<<(N_EDGES + EPB - 1) / EPB, 512, 0, stream>>>(ei, meta, bucket_cursor, ebuf);
    k_bfill2  <<<NBUCK, B, 0, stream>>>(ebuf, bucket_base, row_ptr, dinv, col_idx);

    k_gemm1<<<N_NODES / 8, B, 0, stream>>>(x, W1, dinv, u1);
    k_pull1<<<(N_NODES * 8) / B, B, 0, stream>>>(row_ptr, col_idx, dinv, u1, a1);

    k_gemm2<<<N_NODES / 16, B, 0, stream>>>(a1, b1, W2, dinv, u2);
    k_pull2<<<(N_NODES * 4 + B - 1) / B, B, 0, stream>>>(row_ptr, col_idx, dinv, u2, a2);

    k_final<<<(N_NODES + B - 1) / B, B, 0, stream>>>(a2, b2, Wc, bc, out);
}

// Round 7
// 349.915 us; speedup vs baseline: 6.4311x; 1.0773x over previous
//
#include <hip/hip_runtime.h>
#include <math.h>

#define N_NODES 100000
#define N_EDGES 3200000
#define D_FEAT 128
#define H1 32
#define H2 16
#define NC 8

#define NBUCK 391          // buckets of 256 dst nodes: ceil(100000/256)
#define EPB 8192           // edges per k_bscatter block

// ---------------- detect edge dtype + zero bucket counters ----------------
// int64 little-endian with ids < 2^31 => every odd int32 word is 0.

__global__ void k_detect(const int* __restrict__ ei, int* __restrict__ meta,
                         int* __restrict__ bucket_cnt) {
    __shared__ int red[256];
    int v = 0;
    for (int i = threadIdx.x; i < 1024; i += 256) v |= ei[2 * i + 1];
    red[threadIdx.x] = v;
    __syncthreads();
    for (int s = 128; s > 0; s >>= 1) {
        if (threadIdx.x < (unsigned)s) red[threadIdx.x] |= red[threadIdx.x + s];
        __syncthreads();
    }
    if (threadIdx.x == 0) meta[0] = (red[0] == 0) ? 1 : 0;  // 1 => int64
    for (int i = threadIdx.x; i < NBUCK; i += 256) bucket_cnt[i] = 0;
}

// ---------------- pass A: per-bucket histogram (LDS only) ----------------

__global__ __launch_bounds__(256) void k_hist(const int* __restrict__ ei,
                                              const int* __restrict__ meta,
                                              int* __restrict__ bucket_cnt) {
    __shared__ int bh[NBUCK];
    const int tid = threadIdx.x;
    for (int i = tid; i < NBUCK; i += 256) bh[i] = 0;
    __syncthreads();
    const bool is64 = (meta[0] != 0);
    const int stride = gridDim.x * blockDim.x;
    for (int e = blockIdx.x * blockDim.x + tid; e < N_EDGES; e += stride) {
        const int d = is64 ? ei[2 * N_EDGES + 2 * e] : ei[N_EDGES + e];
        atomicAdd(&bh[d >> 8], 1);
    }
    __syncthreads();
    for (int i = tid; i < NBUCK; i += 256)
        if (bh[i]) atomicAdd(&bucket_cnt[i], bh[i]);
}

// ---------------- bucket scan ----------------

__global__ __launch_bounds__(512) void k_bscan(const int* __restrict__ bucket_cnt,
                                               int* __restrict__ bucket_base,
                                               int* __restrict__ bucket_cursor) {
    __shared__ int h[512];
    const int tid = threadIdx.x;
    const int own = (tid < NBUCK) ? bucket_cnt[tid] : 0;
    h[tid] = own;
    __syncthreads();
    for (int off = 1; off < 512; off <<= 1) {
        const int v = (tid >= off) ? h[tid - off] : 0;
        __syncthreads();
        h[tid] += v;
        __syncthreads();
    }
    const int incl = h[tid];
    if (tid < NBUCK) {
        bucket_base[tid] = incl - own;
        bucket_cursor[tid] = incl - own;
        if (tid == NBUCK - 1) bucket_base[NBUCK] = incl;  // == N_EDGES
    }
}

// ---------------- pass B: bucket-grouped edge scatter (packed int) ----------
// ebuf entry = (src << 8) | (dst & 255): src < 2^17, 25 bits total.

__global__ __launch_bounds__(512) void k_bscatter(const int* __restrict__ ei,
                                                  const int* __restrict__ meta,
                                                  int* __restrict__ bucket_cursor,
                                                  int* __restrict__ ebuf) {
    __shared__ int h[512];
    __shared__ int gb[512];
    __shared__ int rank[512];
    const int tid = threadIdx.x;
    h[tid] = 0; rank[tid] = 0;
    __syncthreads();
    const int e0 = blockIdx.x * EPB;
    const int n = min(EPB, N_EDGES - e0);
    const bool is64 = (meta[0] != 0);
    for (int i = tid; i < n; i += 512) {
        const int e = e0 + i;
        const int d = is64 ? ei[2 * N_EDGES + 2 * e] : ei[N_EDGES + e];
        atomicAdd(&h[d >> 8], 1);
    }
    __syncthreads();
    const int own = h[tid];
    if (tid < NBUCK && own > 0) gb[tid] = atomicAdd(&bucket_cursor[tid], own);
    __syncthreads();
    for (int i = tid; i < n; i += 512) {
        const int e = e0 + i;
        int s, d;
        if (is64) { s = ei[2 * e]; d = ei[2 * N_EDGES + 2 * e]; }
        else      { s = ei[e];     d = ei[N_EDGES + e]; }
        const int b = d >> 8;
        const int r = atomicAdd(&rank[b], 1);
        ebuf[gb[b] + r] = (s << 8) | (d & 255);
    }
}

// ---------------- pass C: per-bucket degree+scan+fill ----------------
// Bucket b owns nodes [256b, 256b+256); row_ptr = bucket_base[b] + local scan.

__global__ __launch_bounds__(512) void k_bfill2(const int* __restrict__ ebuf,
                                                const int* __restrict__ bucket_base,
                                                int* __restrict__ row_ptr,
                                                float* __restrict__ dinv,
                                                int* __restrict__ col_idx) {
    __shared__ int cnt[256];
    __shared__ int sc[256];
    __shared__ int cur[256];
    const int b = blockIdx.x;
    const int tid = threadIdx.x;
    if (tid < 256) cnt[tid] = 0;
    __syncthreads();
    const int eb = bucket_base[b], ee = bucket_base[b + 1];
    for (int i = eb + tid; i < ee; i += 512)
        atomicAdd(&cnt[ebuf[i] & 255], 1);
    __syncthreads();
    int own = 0;
    if (tid < 256) { own = cnt[tid]; sc[tid] = own; }
    __syncthreads();
    for (int off = 1; off < 256; off <<= 1) {
        const int v = (tid < 256 && tid >= off) ? sc[tid - off] : 0;
        __syncthreads();
        if (tid < 256) sc[tid] += v;
        __syncthreads();
    }
    if (tid < 256) {
        const int excl = sc[tid] - own;
        const int v = (b << 8) + tid;
        if (v <= N_NODES) row_ptr[v] = eb + excl;   // v==N_NODES: bucket 390, tid 160
        if (v < N_NODES) dinv[v] = rsqrtf(1.0f + (float)own);  // +1 self-loop
        cur[tid] = eb + excl;
    }
    __syncthreads();
    for (int i = eb + tid; i < ee; i += 512) {
        const int pk = ebuf[i];
        const int slot = atomicAdd(&cur[pk & 255], 1);
        col_idx[slot] = pk >> 8;
    }
}

// ---------------- layer 1 linear: u1 = dinv * (x @ W1) ----------------

__global__ __launch_bounds__(256) void k_gemm1(const float* __restrict__ x,
                                               const float* __restrict__ W1,
                                               const float* __restrict__ dinv,
                                               float* __restrict__ u1) {
    __shared__ float Ws[D_FEAT * H1];   // 16 KB
    __shared__ float xs[8][D_FEAT];     // 4 KB
    const int tid = threadIdx.x;
    for (int i = tid; i < D_FEAT * H1; i += 256) Ws[i] = W1[i];
    const int row0 = blockIdx.x * 8;    // 100000/8 = 12500 exact
    const float4* xg = (const float4*)(x + (size_t)row0 * D_FEAT);
    ((float4*)&xs[0][0])[tid] = xg[tid];
    __syncthreads();
    const int r = tid >> 5;
    const int j = tid & 31;
    float acc = 0.0f;
#pragma unroll 8
    for (int k = 0; k < D_FEAT; ++k)
        acc = fmaf(xs[r][k], Ws[k * H1 + j], acc);
    const int v = row0 + r;
    u1[(size_t)v * H1 + j] = acc * dinv[v];
}

// ---------------- fused pull1 + GEMM2: u2 = dinv*( relu(dinv*(u1self+Σu1[src]) + b1) @ W2 )
// 256 threads = 32 nodes x 8 lanes; grid 3125 exact.

__global__ __launch_bounds__(256) void k_pull1f(const int* __restrict__ row_ptr,
                                                const int* __restrict__ col_idx,
                                                const float* __restrict__ dinv,
                                                const float* __restrict__ u1,
                                                const float* __restrict__ b1,
                                                const float* __restrict__ W2,
                                                float* __restrict__ u2) {
    __shared__ float Ws[H1 * H2];   // 512
    __shared__ float hs[32][33];    // padded: bank-conflict-free row access
    const int tid = threadIdx.x;
    for (int i = tid; i < H1 * H2; i += 256) Ws[i] = W2[i];
    const int n = tid >> 3;         // node-in-block 0..31
    const int l = tid & 7;          // feat-quad lane 0..7
    const int v = blockIdx.x * 32 + n;
    const float4* base = (const float4*)u1;
    float4 acc = base[(size_t)v * 8 + l];   // self-loop term
    const int beg = row_ptr[v];
    const int end = row_ptr[v + 1];
    for (int i = beg; i < end; ++i) {
        const int s = col_idx[i];
        const float4 w = base[(size_t)s * 8 + l];
        acc.x += w.x; acc.y += w.y; acc.z += w.z; acc.w += w.w;
    }
    const float dv = dinv[v];
    const float4 bb = ((const float4*)b1)[l];
    hs[n][l * 4 + 0] = fmaxf(fmaf(acc.x, dv, bb.x), 0.0f);
    hs[n][l * 4 + 1] = fmaxf(fmaf(acc.y, dv, bb.y), 0.0f);
    hs[n][l * 4 + 2] = fmaxf(fmaf(acc.z, dv, bb.z), 0.0f);
    hs[n][l * 4 + 3] = fmaxf(fmaf(acc.w, dv, bb.w), 0.0f);
    __syncthreads();
    // GEMM2: same thread mapping, lane l computes outputs j = 2l, 2l+1 of node n
    const int j0 = l * 2;
    float s0 = 0.0f, s1 = 0.0f;
#pragma unroll
    for (int k = 0; k < H1; ++k) {
        const float hk = hs[n][k];
        s0 = fmaf(hk, Ws[k * H2 + j0], s0);
        s1 = fmaf(hk, Ws[k * H2 + j0 + 1], s1);
    }
    float2 o; o.x = s0 * dv; o.y = s1 * dv;
    ((float2*)u2)[(size_t)v * 8 + l] = o;
}

// ---------------- fused pull2 + classifier + log_softmax --------------------
// 256 threads = 64 nodes x 4 lanes; final matvec one thread per node.

__global__ __launch_bounds__(256) void k_pull2f(const int* __restrict__ row_ptr,
                                                const int* __restrict__ col_idx,
                                                const float* __restrict__ dinv,
                                                const float* __restrict__ u2,
                                                const float* __restrict__ b2,
                                                const float* __restrict__ Wc,
                                                const float* __restrict__ bc,
                                                float* __restrict__ out) {
    __shared__ float hs[64][17];    // padded rows
    __shared__ float Wcs[H2 * NC];  // 128
    __shared__ float bcs[NC];
    const int tid = threadIdx.x;
    if (tid < H2 * NC) Wcs[tid] = Wc[tid];
    if (tid < NC) bcs[tid] = bc[tid];
    const int n = tid >> 2;         // node-in-block 0..63
    const int l = tid & 3;          // feat-quad lane 0..3
    const int v = blockIdx.x * 64 + n;
    if (v < N_NODES) {
        const float4* base = (const float4*)u2;
        float4 acc = base[(size_t)v * 4 + l];   // self-loop term
        const int beg = row_ptr[v];
        const int end = row_ptr[v + 1];
        for (int i = beg; i < end; ++i) {
            const int s = col_idx[i];
            const float4 w = base[(size_t)s * 4 + l];
            acc.x += w.x; acc.y += w.y; acc.z += w.z; acc.w += w.w;
        }
        const float dv = dinv[v];
        const float4 bb = ((const float4*)b2)[l];
        hs[n][l * 4 + 0] = fmaxf(fmaf(acc.x, dv, bb.x), 0.0f);
        hs[n][l * 4 + 1] = fmaxf(fmaf(acc.y, dv, bb.y), 0.0f);
        hs[n][l * 4 + 2] = fmaxf(fmaf(acc.z, dv, bb.z), 0.0f);
        hs[n][l * 4 + 3] = fmaxf(fmaf(acc.w, dv, bb.w), 0.0f);
    }
    __syncthreads();
    if (tid < 64) {
        const int vv = blockIdx.x * 64 + tid;
        if (vv < N_NODES) {
            float lg[NC];
#pragma unroll
            for (int j = 0; j < NC; ++j) lg[j] = bcs[j];
#pragma unroll
            for (int k = 0; k < H2; ++k) {
                const float hk = hs[tid][k];
#pragma unroll
                for (int j = 0; j < NC; ++j)
                    lg[j] = fmaf(hk, Wcs[k * NC + j], lg[j]);
            }
            float m = lg[0];
#pragma unroll
            for (int j = 1; j < NC; ++j) m = fmaxf(m, lg[j]);
            float s = 0.0f;
#pragma unroll
            for (int j = 0; j < NC; ++j) s += expf(lg[j] - m);
            const float lse = logf(s) + m;
            float4 o0, o1;
            o0.x = lg[0] - lse; o0.y = lg[1] - lse;
            o0.z = lg[2] - lse; o0.w = lg[3] - lse;
            o1.x = lg[4] - lse; o1.y = lg[5] - lse;
            o1.z = lg[6] - lse; o1.w = lg[7] - lse;
            float4* op = (float4*)(out + (size_t)vv * NC);
            op[0] = o0; op[1] = o1;
        }
    }
}

// ---------------- host launch ----------------

extern "C" void kernel_launch(void* const* d_in, const int* in_sizes, int n_in,
                              void* d_out, int out_size, void* d_ws, size_t ws_size,
                              hipStream_t stream) {
    const float* x   = (const float*)d_in[0];
    const int*   ei  = (const int*)d_in[1];
    const float* W1  = (const float*)d_in[2];
    const float* b1  = (const float*)d_in[3];
    const float* W2  = (const float*)d_in[4];
    const float* b2  = (const float*)d_in[5];
    const float* Wc  = (const float*)d_in[6];
    const float* bc  = (const float*)d_in[7];
    float* out = (float*)d_out;

    // workspace layout (int units). ~33 MB total.
    int*   meta          = (int*)d_ws;                   // 16
    int*   bucket_cnt    = meta + 16;                    // 512
    int*   bucket_base   = bucket_cnt + 512;             // 512 (NBUCK+1 used)
    int*   bucket_cursor = bucket_base + 512;            // 512
    int*   row_ptr       = bucket_cursor + 512;          // 100016 (100001 used)
    float* dinv          = (float*)(row_ptr + 100016);   // 100000
    int*   col_idx       = (int*)(dinv + 100000);        // 3200000
    int*   ebuf          = col_idx + 3200000;            // 3200000 (packed int)
    // u1 aliases ebuf (dead after k_bfill2); u2 follows.
    float* u1 = (float*)ebuf;                            // 3200000
    float* u2 = u1 + (size_t)N_NODES * H1;               // 1600000

    const int B = 256;
    k_detect  <<<1, B, 0, stream>>>(ei, meta, bucket_cnt);
    k_hist    <<<1024, B, 0, stream>>>(ei, meta, bucket_cnt);
    k_bscan   <<<1, 512, 0, stream>>>(bucket_cnt, bucket_base, bucket_cursor);
    k_bscatter<<<(N_EDGES + EPB - 1) / EPB, 512, 0, stream>>>(ei, meta, bucket_cursor, ebuf);
    k_bfill2  <<<NBUCK, 512, 0, stream>>>(ebuf, bucket_base, row_ptr, dinv, col_idx);

    k_gemm1 <<<N_NODES / 8, B, 0, stream>>>(x, W1, dinv, u1);
    k_pull1f<<<N_NODES / 32, B, 0, stream>>>(row_ptr, col_idx, dinv, u1, b1, W2, u2);
    k_pull2f<<<(N_NODES + 63) / 64, B, 0, stream>>>(row_ptr, col_idx, dinv, u2, b2, Wc, bc, out);
}

// Round 8
// 334.203 us; speedup vs baseline: 6.7335x; 1.0470x over previous
//
#include <hip/hip_runtime.h>
#include <math.h>

#define N_NODES 100000
#define N_EDGES 3200000
#define D_FEAT 128
#define H1 32
#define H2 16
#define NC 8

#define NBUCK 391          // buckets of 256 dst nodes: ceil(100000/256)
#define EPB 8192           // edges per k_bscatter block

// bf16 helpers (round-to-nearest-even pack, shift-expand)
__device__ inline unsigned short f2bf(float f) {
    unsigned int u = __float_as_uint(f);
    u += 0x7FFF + ((u >> 16) & 1);
    return (unsigned short)(u >> 16);
}
__device__ inline float bf2f(unsigned short h) {
    return __uint_as_float((unsigned int)h << 16);
}

// ---------------- detect edge dtype + zero bucket counters ----------------
// int64 little-endian with ids < 2^31 => every odd int32 word is 0.

__global__ void k_detect(const int* __restrict__ ei, int* __restrict__ meta,
                         int* __restrict__ bucket_cnt) {
    __shared__ int red[256];
    int v = 0;
    for (int i = threadIdx.x; i < 1024; i += 256) v |= ei[2 * i + 1];
    red[threadIdx.x] = v;
    __syncthreads();
    for (int s = 128; s > 0; s >>= 1) {
        if (threadIdx.x < (unsigned)s) red[threadIdx.x] |= red[threadIdx.x + s];
        __syncthreads();
    }
    if (threadIdx.x == 0) meta[0] = (red[0] == 0) ? 1 : 0;  // 1 => int64
    for (int i = threadIdx.x; i < NBUCK; i += 256) bucket_cnt[i] = 0;
}

// ---------------- pass A: per-bucket histogram (LDS only) ----------------

__global__ __launch_bounds__(256) void k_hist(const int* __restrict__ ei,
                                              const int* __restrict__ meta,
                                              int* __restrict__ bucket_cnt) {
    __shared__ int bh[NBUCK];
    const int tid = threadIdx.x;
    for (int i = tid; i < NBUCK; i += 256) bh[i] = 0;
    __syncthreads();
    const bool is64 = (meta[0] != 0);
    const int stride = gridDim.x * blockDim.x;
    for (int e = blockIdx.x * blockDim.x + tid; e < N_EDGES; e += stride) {
        const int d = is64 ? ei[2 * N_EDGES + 2 * e] : ei[N_EDGES + e];
        atomicAdd(&bh[d >> 8], 1);
    }
    __syncthreads();
    for (int i = tid; i < NBUCK; i += 256)
        if (bh[i]) atomicAdd(&bucket_cnt[i], bh[i]);
}

// ---------------- bucket scan ----------------

__global__ __launch_bounds__(512) void k_bscan(const int* __restrict__ bucket_cnt,
                                               int* __restrict__ bucket_base,
                                               int* __restrict__ bucket_cursor) {
    __shared__ int h[512];
    const int tid = threadIdx.x;
    const int own = (tid < NBUCK) ? bucket_cnt[tid] : 0;
    h[tid] = own;
    __syncthreads();
    for (int off = 1; off < 512; off <<= 1) {
        const int v = (tid >= off) ? h[tid - off] : 0;
        __syncthreads();
        h[tid] += v;
        __syncthreads();
    }
    const int incl = h[tid];
    if (tid < NBUCK) {
        bucket_base[tid] = incl - own;
        bucket_cursor[tid] = incl - own;
        if (tid == NBUCK - 1) bucket_base[NBUCK] = incl;  // == N_EDGES
    }
}

// ---------------- pass B: bucket-grouped edge scatter (packed int) ----------
// ebuf entry = (src << 8) | (dst & 255): src < 2^17, 25 bits total.

__global__ __launch_bounds__(512) void k_bscatter(const int* __restrict__ ei,
                                                  const int* __restrict__ meta,
                                                  int* __restrict__ bucket_cursor,
                                                  int* __restrict__ ebuf) {
    __shared__ int h[512];
    __shared__ int gb[512];
    __shared__ int rank[512];
    const int tid = threadIdx.x;
    h[tid] = 0; rank[tid] = 0;
    __syncthreads();
    const int e0 = blockIdx.x * EPB;
    const int n = min(EPB, N_EDGES - e0);
    const bool is64 = (meta[0] != 0);
    for (int i = tid; i < n; i += 512) {
        const int e = e0 + i;
        const int d = is64 ? ei[2 * N_EDGES + 2 * e] : ei[N_EDGES + e];
        atomicAdd(&h[d >> 8], 1);
    }
    __syncthreads();
    const int own = h[tid];
    if (tid < NBUCK && own > 0) gb[tid] = atomicAdd(&bucket_cursor[tid], own);
    __syncthreads();
    for (int i = tid; i < n; i += 512) {
        const int e = e0 + i;
        int s, d;
        if (is64) { s = ei[2 * e]; d = ei[2 * N_EDGES + 2 * e]; }
        else      { s = ei[e];     d = ei[N_EDGES + e]; }
        const int b = d >> 8;
        const int r = atomicAdd(&rank[b], 1);
        ebuf[gb[b] + r] = (s << 8) | (d & 255);
    }
}

// ---------------- pass C: per-bucket degree+scan+fill ----------------
// Bucket b owns nodes [256b, 256b+256); row_ptr = bucket_base[b] + local scan.

__global__ __launch_bounds__(512) void k_bfill2(const int* __restrict__ ebuf,
                                                const int* __restrict__ bucket_base,
                                                int* __restrict__ row_ptr,
                                                float* __restrict__ dinv,
                                                int* __restrict__ col_idx) {
    __shared__ int cnt[256];
    __shared__ int sc[256];
    __shared__ int cur[256];
    const int b = blockIdx.x;
    const int tid = threadIdx.x;
    if (tid < 256) cnt[tid] = 0;
    __syncthreads();
    const int eb = bucket_base[b], ee = bucket_base[b + 1];
    for (int i = eb + tid; i < ee; i += 512)
        atomicAdd(&cnt[ebuf[i] & 255], 1);
    __syncthreads();
    int own = 0;
    if (tid < 256) { own = cnt[tid]; sc[tid] = own; }
    __syncthreads();
    for (int off = 1; off < 256; off <<= 1) {
        const int v = (tid < 256 && tid >= off) ? sc[tid - off] : 0;
        __syncthreads();
        if (tid < 256) sc[tid] += v;
        __syncthreads();
    }
    if (tid < 256) {
        const int excl = sc[tid] - own;
        const int v = (b << 8) + tid;
        if (v <= N_NODES) row_ptr[v] = eb + excl;   // v==N_NODES: bucket 390, tid 160
        if (v < N_NODES) dinv[v] = rsqrtf(1.0f + (float)own);  // +1 self-loop
        cur[tid] = eb + excl;
    }
    __syncthreads();
    for (int i = eb + tid; i < ee; i += 512) {
        const int pk = ebuf[i];
        const int slot = atomicAdd(&cur[pk & 255], 1);
        col_idx[slot] = pk >> 8;
    }
}

// ---------------- layer 1 linear: u1b = bf16( dinv * (x @ W1) ) --------------

__global__ __launch_bounds__(256) void k_gemm1(const float* __restrict__ x,
                                               const float* __restrict__ W1,
                                               const float* __restrict__ dinv,
                                               unsigned short* __restrict__ u1b) {
    __shared__ float Ws[D_FEAT * H1];   // 16 KB
    __shared__ float xs[8][D_FEAT];     // 4 KB
    const int tid = threadIdx.x;
    for (int i = tid; i < D_FEAT * H1; i += 256) Ws[i] = W1[i];
    const int row0 = blockIdx.x * 8;    // 100000/8 = 12500 exact
    const float4* xg = (const float4*)(x + (size_t)row0 * D_FEAT);
    ((float4*)&xs[0][0])[tid] = xg[tid];
    __syncthreads();
    const int r = tid >> 5;
    const int j = tid & 31;
    float acc = 0.0f;
#pragma unroll 8
    for (int k = 0; k < D_FEAT; ++k)
        acc = fmaf(xs[r][k], Ws[k * H1 + j], acc);
    const int v = row0 + r;
    u1b[(size_t)v * H1 + j] = f2bf(acc * dinv[v]);
}

// ---------------- fused pull1 + GEMM2 (bf16 gather, f32 accumulate) ----------
// u2b = bf16( dinv*( relu(dinv*(u1self+Σu1[src]) + b1) @ W2 ) )
// 256 threads = 32 nodes x 8 lanes; grid 3125 exact.

__global__ __launch_bounds__(256) void k_pull1f(const int* __restrict__ row_ptr,
                                                const int* __restrict__ col_idx,
                                                const float* __restrict__ dinv,
                                                const unsigned short* __restrict__ u1b,
                                                const float* __restrict__ b1,
                                                const float* __restrict__ W2,
                                                unsigned int* __restrict__ u2b) {
    __shared__ float Ws[H1 * H2];   // 512
    __shared__ float hs[32][33];    // padded: bank-conflict-free row access
    const int tid = threadIdx.x;
    for (int i = tid; i < H1 * H2; i += 256) Ws[i] = W2[i];
    const int n = tid >> 3;         // node-in-block 0..31
    const int l = tid & 7;          // feat-quad lane 0..7
    const int v = blockIdx.x * 32 + n;
    const ushort4* base = (const ushort4*)u1b;   // 4 bf16 = 8B per lane
    ushort4 w = base[(size_t)v * 8 + l];         // self-loop term
    float ax = bf2f(w.x), ay = bf2f(w.y), az = bf2f(w.z), aw = bf2f(w.w);
    const int beg = row_ptr[v];
    const int end = row_ptr[v + 1];
    for (int i = beg; i < end; ++i) {
        const int s = col_idx[i];
        w = base[(size_t)s * 8 + l];
        ax += bf2f(w.x); ay += bf2f(w.y); az += bf2f(w.z); aw += bf2f(w.w);
    }
    const float dv = dinv[v];
    const float4 bb = ((const float4*)b1)[l];
    hs[n][l * 4 + 0] = fmaxf(fmaf(ax, dv, bb.x), 0.0f);
    hs[n][l * 4 + 1] = fmaxf(fmaf(ay, dv, bb.y), 0.0f);
    hs[n][l * 4 + 2] = fmaxf(fmaf(az, dv, bb.z), 0.0f);
    hs[n][l * 4 + 3] = fmaxf(fmaf(aw, dv, bb.w), 0.0f);
    __syncthreads();
    // GEMM2: lane l computes outputs j = 2l, 2l+1 of node n
    const int j0 = l * 2;
    float s0 = 0.0f, s1 = 0.0f;
#pragma unroll
    for (int k = 0; k < H1; ++k) {
        const float hk = hs[n][k];
        s0 = fmaf(hk, Ws[k * H2 + j0], s0);
        s1 = fmaf(hk, Ws[k * H2 + j0 + 1], s1);
    }
    u2b[(size_t)v * 8 + l] =
        (unsigned int)f2bf(s0 * dv) | ((unsigned int)f2bf(s1 * dv) << 16);
}

// ---------------- fused pull2 + classifier + log_softmax (bf16 gather) -------
// 256 threads = 64 nodes x 4 lanes; final matvec one thread per node.

__global__ __launch_bounds__(256) void k_pull2f(const int* __restrict__ row_ptr,
                                                const int* __restrict__ col_idx,
                                                const float* __restrict__ dinv,
                                                const unsigned short* __restrict__ u2b,
                                                const float* __restrict__ b2,
                                                const float* __restrict__ Wc,
                                                const float* __restrict__ bc,
                                                float* __restrict__ out) {
    __shared__ float hs[64][17];    // padded rows
    __shared__ float Wcs[H2 * NC];  // 128
    __shared__ float bcs[NC];
    const int tid = threadIdx.x;
    if (tid < H2 * NC) Wcs[tid] = Wc[tid];
    if (tid < NC) bcs[tid] = bc[tid];
    const int n = tid >> 2;         // node-in-block 0..63
    const int l = tid & 3;          // feat-quad lane 0..3
    const int v = blockIdx.x * 64 + n;
    if (v < N_NODES) {
        const ushort4* base = (const ushort4*)u2b;   // 4 bf16 = 8B per lane
        ushort4 w = base[(size_t)v * 4 + l];         // self-loop term
        float ax = bf2f(w.x), ay = bf2f(w.y), az = bf2f(w.z), aw = bf2f(w.w);
        const int beg = row_ptr[v];
        const int end = row_ptr[v + 1];
        for (int i = beg; i < end; ++i) {
            const int s = col_idx[i];
            w = base[(size_t)s * 4 + l];
            ax += bf2f(w.x); ay += bf2f(w.y); az += bf2f(w.z); aw += bf2f(w.w);
        }
        const float dv = dinv[v];
        const float4 bb = ((const float4*)b2)[l];
        hs[n][l * 4 + 0] = fmaxf(fmaf(ax, dv, bb.x), 0.0f);
        hs[n][l * 4 + 1] = fmaxf(fmaf(ay, dv, bb.y), 0.0f);
        hs[n][l * 4 + 2] = fmaxf(fmaf(az, dv, bb.z), 0.0f);
        hs[n][l * 4 + 3] = fmaxf(fmaf(aw, dv, bb.w), 0.0f);
    }
    __syncthreads();
    if (tid < 64) {
        const int vv = blockIdx.x * 64 + tid;
        if (vv < N_NODES) {
            float lg[NC];
#pragma unroll
            for (int j = 0; j < NC; ++j) lg[j] = bcs[j];
#pragma unroll
            for (int k = 0; k < H2; ++k) {
                const float hk = hs[tid][k];
#pragma unroll
                for (int j = 0; j < NC; ++j)
                    lg[j] = fmaf(hk, Wcs[k * NC + j], lg[j]);
            }
            float m = lg[0];
#pragma unroll
            for (int j = 1; j < NC; ++j) m = fmaxf(m, lg[j]);
            float s = 0.0f;
#pragma unroll
            for (int j = 0; j < NC; ++j) s += expf(lg[j] - m);
            const float lse = logf(s) + m;
            float4 o0, o1;
            o0.x = lg[0] - lse; o0.y = lg[1] - lse;
            o0.z = lg[2] - lse; o0.w = lg[3] - lse;
            o1.x = lg[4] - lse; o1.y = lg[5] - lse;
            o1.z = lg[6] - lse; o1.w = lg[7] - lse;
            float4* op = (float4*)(out + (size_t)vv * NC);
            op[0] = o0; op[1] = o1;
        }
    }
}

// ---------------- host launch ----------------

extern "C" void kernel_launch(void* const* d_in, const int* in_sizes, int n_in,
                              void* d_out, int out_size, void* d_ws, size_t ws_size,
                              hipStream_t stream) {
    const float* x   = (const float*)d_in[0];
    const int*   ei  = (const int*)d_in[1];
    const float* W1  = (const float*)d_in[2];
    const float* b1  = (const float*)d_in[3];
    const float* W2  = (const float*)d_in[4];
    const float* b2  = (const float*)d_in[5];
    const float* Wc  = (const float*)d_in[6];
    const float* bc  = (const float*)d_in[7];
    float* out = (float*)d_out;

    // workspace layout (int units). ~30 MB total.
    int*   meta          = (int*)d_ws;                   // 16
    int*   bucket_cnt    = meta + 16;                    // 512
    int*   bucket_base   = bucket_cnt + 512;             // 512 (NBUCK+1 used)
    int*   bucket_cursor = bucket_base + 512;            // 512
    int*   row_ptr       = bucket_cursor + 512;          // 100016 (100001 used)
    float* dinv          = (float*)(row_ptr + 100016);   // 100000
    int*   col_idx       = (int*)(dinv + 100000);        // 3200000
    int*   ebuf          = col_idx + 3200000;            // 3200000 (packed int)
    // u1b (bf16, 6.4 MB) aliases ebuf (dead after k_bfill2); u2b after ebuf.
    unsigned short* u1b  = (unsigned short*)ebuf;        // 3.2M bf16
    unsigned int*   u2b  = (unsigned int*)(ebuf + 3200000); // 800k uints (1.6M bf16)

    const int B = 256;
    k_detect  <<<1, B, 0, stream>>>(ei, meta, bucket_cnt);
    k_hist    <<<1024, B, 0, stream>>>(ei, meta, bucket_cnt);
    k_bscan   <<<1, 512, 0, stream>>>(bucket_cnt, bucket_base, bucket_cursor);
    k_bscatter<<<(N_EDGES + EPB - 1) / EPB, 512, 0, stream>>>(ei, meta, bucket_cursor, ebuf);
    k_bfill2  <<<NBUCK, 512, 0, stream>>>(ebuf, bucket_base, row_ptr, dinv, col_idx);

    k_gemm1 <<<N_NODES / 8, B, 0, stream>>>(x, W1, dinv, u1b);
    k_pull1f<<<N_NODES / 32, B, 0, stream>>>(row_ptr, col_idx, dinv, u1b, b1, W2, u2b);
    k_pull2f<<<(N_NODES + 63) / 64, B, 0, stream>>>(row_ptr, col_idx, dinv,
                                                    (const unsigned short*)u2b, b2, Wc, bc, out);
}

// Round 9
// 322.631 us; speedup vs baseline: 6.9750x; 1.0359x over previous
//
#include <hip/hip_runtime.h>
#include <math.h>

#define N_NODES 100000
#define N_EDGES 3200000
#define D_FEAT 128
#define H1 32
#define H2 16
#define NC 8

#define NBUCK 391          // buckets of 256 dst nodes: ceil(100000/256)
#define EPB 8192           // edges per k_bscatter block

// bf16 helpers (round-to-nearest-even pack, shift-expand)
__device__ inline unsigned short f2bf(float f) {
    unsigned int u = __float_as_uint(f);
    u += 0x7FFF + ((u >> 16) & 1);
    return (unsigned short)(u >> 16);
}
__device__ inline float bf2f(unsigned short h) {
    return __uint_as_float((unsigned int)h << 16);
}

// ---------------- detect edge dtype + zero bucket counters ----------------
// int64 little-endian with ids < 2^31 => every odd int32 word is 0.

__global__ void k_detect(const int* __restrict__ ei, int* __restrict__ meta,
                         int* __restrict__ bucket_cnt) {
    __shared__ int red[256];
    int v = 0;
    for (int i = threadIdx.x; i < 1024; i += 256) v |= ei[2 * i + 1];
    red[threadIdx.x] = v;
    __syncthreads();
    for (int s = 128; s > 0; s >>= 1) {
        if (threadIdx.x < (unsigned)s) red[threadIdx.x] |= red[threadIdx.x + s];
        __syncthreads();
    }
    if (threadIdx.x == 0) meta[0] = (red[0] == 0) ? 1 : 0;  // 1 => int64
    for (int i = threadIdx.x; i < NBUCK; i += 256) bucket_cnt[i] = 0;
}

// ---------------- pass A: per-bucket histogram (LDS only) ----------------

__global__ __launch_bounds__(256) void k_hist(const int* __restrict__ ei,
                                              const int* __restrict__ meta,
                                              int* __restrict__ bucket_cnt) {
    __shared__ int bh[NBUCK];
    const int tid = threadIdx.x;
    for (int i = tid; i < NBUCK; i += 256) bh[i] = 0;
    __syncthreads();
    const bool is64 = (meta[0] != 0);
    const int stride = gridDim.x * blockDim.x;
    for (int e = blockIdx.x * blockDim.x + tid; e < N_EDGES; e += stride) {
        const int d = is64 ? ei[2 * N_EDGES + 2 * e] : ei[N_EDGES + e];
        atomicAdd(&bh[d >> 8], 1);
    }
    __syncthreads();
    for (int i = tid; i < NBUCK; i += 256)
        if (bh[i]) atomicAdd(&bucket_cnt[i], bh[i]);
}

// ---------------- bucket scan ----------------

__global__ __launch_bounds__(512) void k_bscan(const int* __restrict__ bucket_cnt,
                                               int* __restrict__ bucket_base,
                                               int* __restrict__ bucket_cursor) {
    __shared__ int h[512];
    const int tid = threadIdx.x;
    const int own = (tid < NBUCK) ? bucket_cnt[tid] : 0;
    h[tid] = own;
    __syncthreads();
    for (int off = 1; off < 512; off <<= 1) {
        const int v = (tid >= off) ? h[tid - off] : 0;
        __syncthreads();
        h[tid] += v;
        __syncthreads();
    }
    const int incl = h[tid];
    if (tid < NBUCK) {
        bucket_base[tid] = incl - own;
        bucket_cursor[tid] = incl - own;
        if (tid == NBUCK - 1) bucket_base[NBUCK] = incl;  // == N_EDGES
    }
}

// ---------------- pass B: bucket-grouped edge scatter (packed int) ----------
// ebuf entry = (src << 8) | (dst & 255): src < 2^17, 25 bits total.

__global__ __launch_bounds__(512) void k_bscatter(const int* __restrict__ ei,
                                                  const int* __restrict__ meta,
                                                  int* __restrict__ bucket_cursor,
                                                  int* __restrict__ ebuf) {
    __shared__ int h[512];
    __shared__ int gb[512];
    __shared__ int rank[512];
    const int tid = threadIdx.x;
    h[tid] = 0; rank[tid] = 0;
    __syncthreads();
    const int e0 = blockIdx.x * EPB;
    const int n = min(EPB, N_EDGES - e0);
    const bool is64 = (meta[0] != 0);
    for (int i = tid; i < n; i += 512) {
        const int e = e0 + i;
        const int d = is64 ? ei[2 * N_EDGES + 2 * e] : ei[N_EDGES + e];
        atomicAdd(&h[d >> 8], 1);
    }
    __syncthreads();
    const int own = h[tid];
    if (tid < NBUCK && own > 0) gb[tid] = atomicAdd(&bucket_cursor[tid], own);
    __syncthreads();
    for (int i = tid; i < n; i += 512) {
        const int e = e0 + i;
        int s, d;
        if (is64) { s = ei[2 * e]; d = ei[2 * N_EDGES + 2 * e]; }
        else      { s = ei[e];     d = ei[N_EDGES + e]; }
        const int b = d >> 8;
        const int r = atomicAdd(&rank[b], 1);
        ebuf[gb[b] + r] = (s << 8) | (d & 255);
    }
}

// ---------------- pass C: per-bucket degree+scan+fill ----------------
// Bucket b owns nodes [256b, 256b+256); row_ptr = bucket_base[b] + local scan.

__global__ __launch_bounds__(512) void k_bfill2(const int* __restrict__ ebuf,
                                                const int* __restrict__ bucket_base,
                                                int* __restrict__ row_ptr,
                                                float* __restrict__ dinv,
                                                int* __restrict__ col_idx) {
    __shared__ int cnt[256];
    __shared__ int sc[256];
    __shared__ int cur[256];
    const int b = blockIdx.x;
    const int tid = threadIdx.x;
    if (tid < 256) cnt[tid] = 0;
    __syncthreads();
    const int eb = bucket_base[b], ee = bucket_base[b + 1];
    for (int i = eb + tid; i < ee; i += 512)
        atomicAdd(&cnt[ebuf[i] & 255], 1);
    __syncthreads();
    int own = 0;
    if (tid < 256) { own = cnt[tid]; sc[tid] = own; }
    __syncthreads();
    for (int off = 1; off < 256; off <<= 1) {
        const int v = (tid < 256 && tid >= off) ? sc[tid - off] : 0;
        __syncthreads();
        if (tid < 256) sc[tid] += v;
        __syncthreads();
    }
    if (tid < 256) {
        const int excl = sc[tid] - own;
        const int v = (b << 8) + tid;
        if (v <= N_NODES) row_ptr[v] = eb + excl;   // v==N_NODES: bucket 390, tid 160
        if (v < N_NODES) dinv[v] = rsqrtf(1.0f + (float)own);  // +1 self-loop
        cur[tid] = eb + excl;
    }
    __syncthreads();
    for (int i = eb + tid; i < ee; i += 512) {
        const int pk = ebuf[i];
        const int slot = atomicAdd(&cur[pk & 255], 1);
        col_idx[slot] = pk >> 8;
    }
}

// ---------------- layer 1 linear: u1q = fp8_e4m3( dinv * (x @ W1) ) ----------
// fp8 table = 3.2 MB -> fits a single XCD's 4 MB L2 -> gather becomes L2-hit.

__global__ __launch_bounds__(256) void k_gemm1(const float* __restrict__ x,
                                               const float* __restrict__ W1,
                                               const float* __restrict__ dinv,
                                               unsigned int* __restrict__ u1q) {
    __shared__ float Ws[D_FEAT * H1];   // 16 KB
    __shared__ float xs[8][D_FEAT];     // 4 KB
    __shared__ float os[8][33];         // staging for fp8 pack
    const int tid = threadIdx.x;
    for (int i = tid; i < D_FEAT * H1; i += 256) Ws[i] = W1[i];
    const int row0 = blockIdx.x * 8;    // 100000/8 = 12500 exact
    const float4* xg = (const float4*)(x + (size_t)row0 * D_FEAT);
    ((float4*)&xs[0][0])[tid] = xg[tid];
    __syncthreads();
    const int r = tid >> 5;
    const int j = tid & 31;
    float acc = 0.0f;
#pragma unroll 8
    for (int k = 0; k < D_FEAT; ++k)
        acc = fmaf(xs[r][k], Ws[k * H1 + j], acc);
    os[r][j] = acc * dinv[row0 + r];
    __syncthreads();
    if (tid < 64) {   // 8 rows x 8 dwords: pack 4 fp8 per dword
        const int row = tid >> 3, d = tid & 7;
        const float* p = &os[row][d * 4];
        unsigned int pk = __builtin_amdgcn_cvt_pk_fp8_f32(p[0], p[1], 0u, false);
        pk = __builtin_amdgcn_cvt_pk_fp8_f32(p[2], p[3], pk, true);
        u1q[(size_t)(row0 + row) * 8 + d] = pk;
    }
}

// ---------------- fused pull1 + GEMM2 (fp8 gather, f32 accumulate) ----------
// u2b = bf16( dinv*( relu(dinv*(u1self+Σu1[src]) + b1) @ W2 ) )
// 256 threads = 32 nodes x 8 lanes (1 dword = 4 fp8 feats each); grid 3125.

__global__ __launch_bounds__(256) void k_pull1f(const int* __restrict__ row_ptr,
                                                const int* __restrict__ col_idx,
                                                const float* __restrict__ dinv,
                                                const unsigned int* __restrict__ u1q,
                                                const float* __restrict__ b1,
                                                const float* __restrict__ W2,
                                                unsigned int* __restrict__ u2b) {
    __shared__ float Ws[H1 * H2];   // 512
    __shared__ float hs[32][33];    // padded: bank-conflict-free row access
    const int tid = threadIdx.x;
    for (int i = tid; i < H1 * H2; i += 256) Ws[i] = W2[i];
    const int n = tid >> 3;         // node-in-block 0..31
    const int l = tid & 7;          // feat-quad lane 0..7
    const int v = blockIdx.x * 32 + n;
    unsigned int q = u1q[(size_t)v * 8 + l];   // self-loop term
    float ax = __builtin_amdgcn_cvt_f32_fp8(q, 0);
    float ay = __builtin_amdgcn_cvt_f32_fp8(q, 1);
    float az = __builtin_amdgcn_cvt_f32_fp8(q, 2);
    float aw = __builtin_amdgcn_cvt_f32_fp8(q, 3);
    const int beg = row_ptr[v];
    const int end = row_ptr[v + 1];
    for (int i = beg; i < end; ++i) {
        const int s = col_idx[i];
        q = u1q[(size_t)s * 8 + l];
        ax += __builtin_amdgcn_cvt_f32_fp8(q, 0);
        ay += __builtin_amdgcn_cvt_f32_fp8(q, 1);
        az += __builtin_amdgcn_cvt_f32_fp8(q, 2);
        aw += __builtin_amdgcn_cvt_f32_fp8(q, 3);
    }
    const float dv = dinv[v];
    const float4 bb = ((const float4*)b1)[l];
    hs[n][l * 4 + 0] = fmaxf(fmaf(ax, dv, bb.x), 0.0f);
    hs[n][l * 4 + 1] = fmaxf(fmaf(ay, dv, bb.y), 0.0f);
    hs[n][l * 4 + 2] = fmaxf(fmaf(az, dv, bb.z), 0.0f);
    hs[n][l * 4 + 3] = fmaxf(fmaf(aw, dv, bb.w), 0.0f);
    __syncthreads();
    // GEMM2: lane l computes outputs j = 2l, 2l+1 of node n
    const int j0 = l * 2;
    float s0 = 0.0f, s1 = 0.0f;
#pragma unroll
    for (int k = 0; k < H1; ++k) {
        const float hk = hs[n][k];
        s0 = fmaf(hk, Ws[k * H2 + j0], s0);
        s1 = fmaf(hk, Ws[k * H2 + j0 + 1], s1);
    }
    u2b[(size_t)v * 8 + l] =
        (unsigned int)f2bf(s0 * dv) | ((unsigned int)f2bf(s1 * dv) << 16);
}

// ---------------- fused pull2 + classifier + log_softmax (bf16 gather) -------
// 256 threads = 64 nodes x 4 lanes; final matvec one thread per node.

__global__ __launch_bounds__(256) void k_pull2f(const int* __restrict__ row_ptr,
                                                const int* __restrict__ col_idx,
                                                const float* __restrict__ dinv,
                                                const unsigned short* __restrict__ u2b,
                                                const float* __restrict__ b2,
                                                const float* __restrict__ Wc,
                                                const float* __restrict__ bc,
                                                float* __restrict__ out) {
    __shared__ float hs[64][17];    // padded rows
    __shared__ float Wcs[H2 * NC];  // 128
    __shared__ float bcs[NC];
    const int tid = threadIdx.x;
    if (tid < H2 * NC) Wcs[tid] = Wc[tid];
    if (tid < NC) bcs[tid] = bc[tid];
    const int n = tid >> 2;         // node-in-block 0..63
    const int l = tid & 3;          // feat-quad lane 0..3
    const int v = blockIdx.x * 64 + n;
    if (v < N_NODES) {
        const ushort4* base = (const ushort4*)u2b;   // 4 bf16 = 8B per lane
        ushort4 w = base[(size_t)v * 4 + l];         // self-loop term
        float ax = bf2f(w.x), ay = bf2f(w.y), az = bf2f(w.z), aw = bf2f(w.w);
        const int beg = row_ptr[v];
        const int end = row_ptr[v + 1];
        for (int i = beg; i < end; ++i) {
            const int s = col_idx[i];
            w = base[(size_t)s * 4 + l];
            ax += bf2f(w.x); ay += bf2f(w.y); az += bf2f(w.z); aw += bf2f(w.w);
        }
        const float dv = dinv[v];
        const float4 bb = ((const float4*)b2)[l];
        hs[n][l * 4 + 0] = fmaxf(fmaf(ax, dv, bb.x), 0.0f);
        hs[n][l * 4 + 1] = fmaxf(fmaf(ay, dv, bb.y), 0.0f);
        hs[n][l * 4 + 2] = fmaxf(fmaf(az, dv, bb.z), 0.0f);
        hs[n][l * 4 + 3] = fmaxf(fmaf(aw, dv, bb.w), 0.0f);
    }
    __syncthreads();
    if (tid < 64) {
        const int vv = blockIdx.x * 64 + tid;
        if (vv < N_NODES) {
            float lg[NC];
#pragma unroll
            for (int j = 0; j < NC; ++j) lg[j] = bcs[j];
#pragma unroll
            for (int k = 0; k < H2; ++k) {
                const float hk = hs[tid][k];
#pragma unroll
                for (int j = 0; j < NC; ++j)
                    lg[j] = fmaf(hk, Wcs[k * NC + j], lg[j]);
            }
            float m = lg[0];
#pragma unroll
            for (int j = 1; j < NC; ++j) m = fmaxf(m, lg[j]);
            float s = 0.0f;
#pragma unroll
            for (int j = 0; j < NC; ++j) s += expf(lg[j] - m);
            const float lse = logf(s) + m;
            float4 o0, o1;
            o0.x = lg[0] - lse; o0.y = lg[1] - lse;
            o0.z = lg[2] - lse; o0.w = lg[3] - lse;
            o1.x = lg[4] - lse; o1.y = lg[5] - lse;
            o1.z = lg[6] - lse; o1.w = lg[7] - lse;
            float4* op = (float4*)(out + (size_t)vv * NC);
            op[0] = o0; op[1] = o1;
        }
    }
}

// ---------------- host launch ----------------

extern "C" void kernel_launch(void* const* d_in, const int* in_sizes, int n_in,
                              void* d_out, int out_size, void* d_ws, size_t ws_size,
                              hipStream_t stream) {
    const float* x   = (const float*)d_in[0];
    const int*   ei  = (const int*)d_in[1];
    const float* W1  = (const float*)d_in[2];
    const float* b1  = (const float*)d_in[3];
    const float* W2  = (const float*)d_in[4];
    const float* b2  = (const float*)d_in[5];
    const float* Wc  = (const float*)d_in[6];
    const float* bc  = (const float*)d_in[7];
    float* out = (float*)d_out;

    // workspace layout (int units). ~30 MB total.
    int*   meta          = (int*)d_ws;                   // 16
    int*   bucket_cnt    = meta + 16;                    // 512
    int*   bucket_base   = bucket_cnt + 512;             // 512 (NBUCK+1 used)
    int*   bucket_cursor = bucket_base + 512;            // 512
    int*   row_ptr       = bucket_cursor + 512;          // 100016 (100001 used)
    float* dinv          = (float*)(row_ptr + 100016);   // 100000
    int*   col_idx       = (int*)(dinv + 100000);        // 3200000
    int*   ebuf          = col_idx + 3200000;            // 3200000 (packed int)
    // u1q (fp8, 3.2 MB = 800k dwords) aliases ebuf (dead after k_bfill2);
    // u2b (bf16, 3.2 MB = 800k dwords) placed beyond ebuf.
    unsigned int* u1q    = (unsigned int*)ebuf;          // 800000 dwords
    unsigned int* u2b    = (unsigned int*)(ebuf + 3200000); // 800000 dwords

    const int B = 256;
    k_detect  <<<1, B, 0, stream>>>(ei, meta, bucket_cnt);
    k_hist    <<<1024, B, 0, stream>>>(ei, meta, bucket_cnt);
    k_bscan   <<<1, 512, 0, stream>>>(bucket_cnt, bucket_base, bucket_cursor);
    k_bscatter<<<(N_EDGES + EPB - 1) / EPB, 512, 0, stream>>>(ei, meta, bucket_cursor, ebuf);
    k_bfill2  <<<NBUCK, 512, 0, stream>>>(ebuf, bucket_base, row_ptr, dinv, col_idx);

    k_gemm1 <<<N_NODES / 8, B, 0, stream>>>(x, W1, dinv, u1q);
    k_pull1f<<<N_NODES / 32, B, 0, stream>>>(row_ptr, col_idx, dinv, u1q, b1, W2, u2b);
    k_pull2f<<<(N_NODES + 63) / 64, B, 0, stream>>>(row_ptr, col_idx, dinv,
                                                    (const unsigned short*)u2b, b2, Wc, bc, out);
}

// Round 10
// 273.902 us; speedup vs baseline: 8.2159x; 1.1779x over previous
//
#include <hip/hip_runtime.h>
#include <math.h>

#define N_NODES 100000
#define N_EDGES 3200000
#define D_FEAT 128
#define H1 32
#define H2 16
#define NC 8

#define NBUCK 391          // buckets of 256 dst nodes: ceil(100000/256)
#define BCAP 16384         // fixed ebuf slots per bucket (mean 8184, sigma ~90 -> 90-sigma margin)
#define EPB 8192           // edges per k_bscatter block

typedef short s16x8 __attribute__((ext_vector_type(8)));
typedef float f32x4 __attribute__((ext_vector_type(4)));

// bf16 helpers (round-to-nearest-even pack, shift-expand)
__device__ inline unsigned short f2bf(float f) {
    unsigned int u = __float_as_uint(f);
    u += 0x7FFF + ((u >> 16) & 1);
    return (unsigned short)(u >> 16);
}
__device__ inline float bf2f(unsigned short h) {
    return __uint_as_float((unsigned int)h << 16);
}

// ---------------- detect edge dtype + zero cursors + W1 B-fragment prep ------
// int64 little-endian with ids < 2^31 => every odd int32 word is 0.
// W1f: mfma_f32_16x16x32_bf16 B-operand fragments, ordered [nt][kk][lane][j]:
//   lane holds B[k = (lane>>4)*8 + j][n = lane&15] of the (kk,nt) 32x16 tile.

__global__ void k_detect(const int* __restrict__ ei, const float* __restrict__ W1,
                         int* __restrict__ meta, int* __restrict__ bucket_cursor,
                         unsigned short* __restrict__ W1f) {
    __shared__ int red[256];
    int v = 0;
    for (int i = threadIdx.x; i < 1024; i += 256) v |= ei[2 * i + 1];
    red[threadIdx.x] = v;
    __syncthreads();
    for (int s = 128; s > 0; s >>= 1) {
        if (threadIdx.x < (unsigned)s) red[threadIdx.x] |= red[threadIdx.x + s];
        __syncthreads();
    }
    if (threadIdx.x == 0) meta[0] = (red[0] == 0) ? 1 : 0;  // 1 => int64
    for (int i = threadIdx.x; i < NBUCK; i += 256) bucket_cursor[i] = 0;
    for (int idx = threadIdx.x; idx < 2 * 4 * 64 * 8; idx += 256) {
        const int j    = idx & 7;
        const int lane = (idx >> 3) & 63;
        const int kk   = (idx >> 9) & 3;
        const int nt   = idx >> 11;
        const int k = kk * 32 + ((lane >> 4) << 3) + j;
        const int n = nt * 16 + (lane & 15);
        W1f[idx] = f2bf(W1[k * H1 + n]);
    }
}

// ---------------- pass A: bucket-grouped edge scatter (fixed-cap regions) ----
// ebuf entry = (src << 8) | (dst & 255). Region for bucket b = [b*BCAP, ...).
// No pre-histogram needed: cursors count from 0 inside each region.

__global__ __launch_bounds__(512) void k_bscatter(const int* __restrict__ ei,
                                                  const int* __restrict__ meta,
                                                  int* __restrict__ bucket_cursor,
                                                  int* __restrict__ ebuf) {
    __shared__ int h[512];
    __shared__ int gb[512];
    __shared__ int rank[512];
    const int tid = threadIdx.x;
    h[tid] = 0; rank[tid] = 0;
    __syncthreads();
    const int e0 = blockIdx.x * EPB;
    const int n = min(EPB, N_EDGES - e0);
    const bool is64 = (meta[0] != 0);
    for (int i = tid; i < n; i += 512) {
        const int e = e0 + i;
        const int d = is64 ? ei[2 * N_EDGES + 2 * e] : ei[N_EDGES + e];
        atomicAdd(&h[d >> 8], 1);
    }
    __syncthreads();
    const int own = h[tid];
    if (tid < NBUCK && own > 0)
        gb[tid] = tid * BCAP + atomicAdd(&bucket_cursor[tid], own);
    __syncthreads();
    for (int i = tid; i < n; i += 512) {
        const int e = e0 + i;
        int s, d;
        if (is64) { s = ei[2 * e]; d = ei[2 * N_EDGES + 2 * e]; }
        else      { s = ei[e];     d = ei[N_EDGES + e]; }
        const int b = d >> 8;
        const int r = atomicAdd(&rank[b], 1);
        ebuf[gb[b] + r] = (s << 8) | (d & 255);
    }
}

// ---------------- bucket scan (post-scatter: cursors hold final counts) ------

__global__ __launch_bounds__(512) void k_bscan(const int* __restrict__ bucket_cursor,
                                               int* __restrict__ bucket_base) {
    __shared__ int h[512];
    const int tid = threadIdx.x;
    const int own = (tid < NBUCK) ? bucket_cursor[tid] : 0;
    h[tid] = own;
    __syncthreads();
    for (int off = 1; off < 512; off <<= 1) {
        const int v = (tid >= off) ? h[tid - off] : 0;
        __syncthreads();
        h[tid] += v;
        __syncthreads();
    }
    const int incl = h[tid];
    if (tid < NBUCK) {
        bucket_base[tid] = incl - own;
        if (tid == NBUCK - 1) bucket_base[NBUCK] = incl;  // == N_EDGES
    }
}

// ---------------- pass B: per-bucket degree+scan+fill ----------------
// Bucket b owns nodes [256b, 256b+256); reads its ebuf region at b*BCAP,
// writes its col_idx window at bucket_base[b]; emits row_ptr + dinv.

__global__ __launch_bounds__(512) void k_bfill2(const int* __restrict__ ebuf,
                                                const int* __restrict__ bucket_base,
                                                int* __restrict__ row_ptr,
                                                float* __restrict__ dinv,
                                                int* __restrict__ col_idx) {
    __shared__ int cnt[256];
    __shared__ int sc[256];
    __shared__ int cur[256];
    const int b = blockIdx.x;
    const int tid = threadIdx.x;
    if (tid < 256) cnt[tid] = 0;
    __syncthreads();
    const int wb = bucket_base[b];
    const int nb = bucket_base[b + 1] - wb;
    const int rb = b * BCAP;
    for (int i = tid; i < nb; i += 512)
        atomicAdd(&cnt[ebuf[rb + i] & 255], 1);
    __syncthreads();
    int own = 0;
    if (tid < 256) { own = cnt[tid]; sc[tid] = own; }
    __syncthreads();
    for (int off = 1; off < 256; off <<= 1) {
        const int v = (tid < 256 && tid >= off) ? sc[tid - off] : 0;
        __syncthreads();
        if (tid < 256) sc[tid] += v;
        __syncthreads();
    }
    if (tid < 256) {
        const int excl = sc[tid] - own;
        const int v = (b << 8) + tid;
        if (v <= N_NODES) row_ptr[v] = wb + excl;   // v==N_NODES: bucket 390, tid 160
        if (v < N_NODES) dinv[v] = rsqrtf(1.0f + (float)own);  // +1 self-loop
        cur[tid] = wb + excl;
    }
    __syncthreads();
    for (int i = tid; i < nb; i += 512) {
        const int pk = ebuf[rb + i];
        const int slot = atomicAdd(&cur[pk & 255], 1);
        col_idx[slot] = pk >> 8;
    }
}

// ---------------- layer 1 linear via MFMA: u1q = fp8( dinv * (x @ W1) ) ------
// Wave = 16 rows x 32 cols, K=128: 8x mfma_f32_16x16x32_bf16. A from x (f32->
// bf16 on the fly, 32B/lane contiguous), B from precomputed W1f fragments.
// C/D layout (verified m89): col=lane&15, row=(lane>>4)*4+reg. Routed through
// LDS for the per-row fp8 pack. Block = 4 waves = 64 rows; grid 1563.

__global__ __launch_bounds__(256) void k_gemm1m(const float* __restrict__ x,
                                                const unsigned short* __restrict__ W1f,
                                                const float* __restrict__ dinv,
                                                unsigned int* __restrict__ u1q) {
    __shared__ float os[4][16][33];
    const int tid = threadIdx.x;
    const int w = tid >> 6;
    const int lane = tid & 63;
    const int row0 = (blockIdx.x * 4 + w) * 16;
    const bool act = (row0 < N_NODES);
    if (act) {
        const int m = lane & 15;
        const int quad = lane >> 4;
        const s16x8* bf = (const s16x8*)W1f;
        f32x4 acc0 = {0.f, 0.f, 0.f, 0.f};
        f32x4 acc1 = {0.f, 0.f, 0.f, 0.f};
#pragma unroll
        for (int kk = 0; kk < 4; ++kk) {
            const float* xp = x + (size_t)(row0 + m) * D_FEAT + kk * 32 + quad * 8;
            const float4 p0 = ((const float4*)xp)[0];
            const float4 p1 = ((const float4*)xp)[1];
            s16x8 a;
            a[0] = (short)f2bf(p0.x); a[1] = (short)f2bf(p0.y);
            a[2] = (short)f2bf(p0.z); a[3] = (short)f2bf(p0.w);
            a[4] = (short)f2bf(p1.x); a[5] = (short)f2bf(p1.y);
            a[6] = (short)f2bf(p1.z); a[7] = (short)f2bf(p1.w);
            acc0 = __builtin_amdgcn_mfma_f32_16x16x32_bf16(a, bf[kk * 64 + lane], acc0, 0, 0, 0);
            acc1 = __builtin_amdgcn_mfma_f32_16x16x32_bf16(a, bf[(4 + kk) * 64 + lane], acc1, 0, 0, 0);
        }
#pragma unroll
        for (int r = 0; r < 4; ++r) {
            os[w][quad * 4 + r][m]      = acc0[r];
            os[w][quad * 4 + r][16 + m] = acc1[r];
        }
    }
    __syncthreads();
    if (act) {
        const int rl = lane >> 2;       // row-in-wave 0..15
        const int seg = lane & 3;       // 8-col segment
        const int row = row0 + rl;
        const float dv = dinv[row];
        const float* p = &os[w][rl][seg * 8];
        unsigned int pk0 = __builtin_amdgcn_cvt_pk_fp8_f32(p[0] * dv, p[1] * dv, 0u, false);
        pk0 = __builtin_amdgcn_cvt_pk_fp8_f32(p[2] * dv, p[3] * dv, pk0, true);
        unsigned int pk1 = __builtin_amdgcn_cvt_pk_fp8_f32(p[4] * dv, p[5] * dv, 0u, false);
        pk1 = __builtin_amdgcn_cvt_pk_fp8_f32(p[6] * dv, p[7] * dv, pk1, true);
        uint2 o; o.x = pk0; o.y = pk1;
        ((uint2*)u1q)[(size_t)row * 4 + seg] = o;
    }
}

// ---------------- fused pull1 + GEMM2 (fp8 gather, 4 lanes/node x 8B) --------
// u2b = bf16( dinv*( relu(dinv*(u1self+Σu1[src]) + b1) @ W2 ) ); 64 nodes/block.

__global__ __launch_bounds__(256) void k_pull1f(const int* __restrict__ row_ptr,
                                                const int* __restrict__ col_idx,
                                                const float* __restrict__ dinv,
                                                const unsigned int* __restrict__ u1q,
                                                const float* __restrict__ b1,
                                                const float* __restrict__ W2,
                                                unsigned int* __restrict__ u2b) {
    __shared__ float Ws[H1 * H2];   // 512
    __shared__ float hs[64][33];    // padded rows
    const int tid = threadIdx.x;
    for (int i = tid; i < H1 * H2; i += 256) Ws[i] = W2[i];
    const int n = tid >> 2;         // node-in-block 0..63
    const int l = tid & 2 ? (tid & 3) : (tid & 3);  // lane 0..3
    const int v = blockIdx.x * 64 + n;
    float dv = 0.0f;
    if (v < N_NODES) {
        const uint2* base = (const uint2*)u1q;      // 8 fp8 per uint2
        uint2 q = base[(size_t)v * 4 + (tid & 3)];  // self-loop term
        float a0 = __builtin_amdgcn_cvt_f32_fp8(q.x, 0);
        float a1 = __builtin_amdgcn_cvt_f32_fp8(q.x, 1);
        float a2 = __builtin_amdgcn_cvt_f32_fp8(q.x, 2);
        float a3 = __builtin_amdgcn_cvt_f32_fp8(q.x, 3);
        float a4 = __builtin_amdgcn_cvt_f32_fp8(q.y, 0);
        float a5 = __builtin_amdgcn_cvt_f32_fp8(q.y, 1);
        float a6 = __builtin_amdgcn_cvt_f32_fp8(q.y, 2);
        float a7 = __builtin_amdgcn_cvt_f32_fp8(q.y, 3);
        const int beg = row_ptr[v];
        const int end = row_ptr[v + 1];
        for (int i = beg; i < end; ++i) {
            const int s = col_idx[i];
            q = base[(size_t)s * 4 + (tid & 3)];
            a0 += __builtin_amdgcn_cvt_f32_fp8(q.x, 0);
            a1 += __builtin_amdgcn_cvt_f32_fp8(q.x, 1);
            a2 += __builtin_amdgcn_cvt_f32_fp8(q.x, 2);
            a3 += __builtin_amdgcn_cvt_f32_fp8(q.x, 3);
            a4 += __builtin_amdgcn_cvt_f32_fp8(q.y, 0);
            a5 += __builtin_amdgcn_cvt_f32_fp8(q.y, 1);
            a6 += __builtin_amdgcn_cvt_f32_fp8(q.y, 2);
            a7 += __builtin_amdgcn_cvt_f32_fp8(q.y, 3);
        }
        dv = dinv[v];
        const int lq = tid & 3;
        const float4 bb0 = ((const float4*)b1)[lq * 2];
        const float4 bb1 = ((const float4*)b1)[lq * 2 + 1];
        float* hp = &hs[n][lq * 8];
        hp[0] = fmaxf(fmaf(a0, dv, bb0.x), 0.0f);
        hp[1] = fmaxf(fmaf(a1, dv, bb0.y), 0.0f);
        hp[2] = fmaxf(fmaf(a2, dv, bb0.z), 0.0f);
        hp[3] = fmaxf(fmaf(a3, dv, bb0.w), 0.0f);
        hp[4] = fmaxf(fmaf(a4, dv, bb1.x), 0.0f);
        hp[5] = fmaxf(fmaf(a5, dv, bb1.y), 0.0f);
        hp[6] = fmaxf(fmaf(a6, dv, bb1.z), 0.0f);
        hp[7] = fmaxf(fmaf(a7, dv, bb1.w), 0.0f);
    }
    __syncthreads();
    if (v < N_NODES) {
        const int j0 = (tid & 3) * 4;
        float s0 = 0.f, s1 = 0.f, s2 = 0.f, s3 = 0.f;
#pragma unroll
        for (int k = 0; k < H1; ++k) {
            const float hk = hs[n][k];
            s0 = fmaf(hk, Ws[k * H2 + j0 + 0], s0);
            s1 = fmaf(hk, Ws[k * H2 + j0 + 1], s1);
            s2 = fmaf(hk, Ws[k * H2 + j0 + 2], s2);
            s3 = fmaf(hk, Ws[k * H2 + j0 + 3], s3);
        }
        uint2 o;
        o.x = (unsigned int)f2bf(s0 * dv) | ((unsigned int)f2bf(s1 * dv) << 16);
        o.y = (unsigned int)f2bf(s2 * dv) | ((unsigned int)f2bf(s3 * dv) << 16);
        ((uint2*)u2b)[(size_t)v * 4 + (tid & 3)] = o;
    }
}

// ---------------- fused pull2 + classifier + log_softmax (2 lanes/node x 16B)-

__global__ __launch_bounds__(256) void k_pull2f(const int* __restrict__ row_ptr,
                                                const int* __restrict__ col_idx,
                                                const float* __restrict__ dinv,
                                                const unsigned int* __restrict__ u2b,
                                                const float* __restrict__ b2,
                                                const float* __restrict__ Wc,
                                                const float* __restrict__ bc,
                                                float* __restrict__ out) {
    __shared__ float hs[128][17];   // padded rows
    __shared__ float Wcs[H2 * NC];  // 128
    __shared__ float bcs[NC];
    const int tid = threadIdx.x;
    if (tid < H2 * NC) Wcs[tid] = Wc[tid];
    if (tid < NC) bcs[tid] = bc[tid];
    const int n = tid >> 1;         // node-in-block 0..127
    const int l = tid & 1;          // lane 0..1 (8 bf16 = 16B each)
    const int v = blockIdx.x * 128 + n;
    if (v < N_NODES) {
        const uint4* base = (const uint4*)u2b;      // 8 bf16 per uint4
        uint4 q = base[(size_t)v * 2 + l];          // self-loop term
        float a0 = bf2f((unsigned short)q.x), a1 = bf2f((unsigned short)(q.x >> 16));
        float a2 = bf2f((unsigned short)q.y), a3 = bf2f((unsigned short)(q.y >> 16));
        float a4 = bf2f((unsigned short)q.z), a5 = bf2f((unsigned short)(q.z >> 16));
        float a6 = bf2f((unsigned short)q.w), a7 = bf2f((unsigned short)(q.w >> 16));
        const int beg = row_ptr[v];
        const int end = row_ptr[v + 1];
        for (int i = beg; i < end; ++i) {
            const int s = col_idx[i];
            q = base[(size_t)s * 2 + l];
            a0 += bf2f((unsigned short)q.x); a1 += bf2f((unsigned short)(q.x >> 16));
            a2 += bf2f((unsigned short)q.y); a3 += bf2f((unsigned short)(q.y >> 16));
            a4 += bf2f((unsigned short)q.z); a5 += bf2f((unsigned short)(q.z >> 16));
            a6 += bf2f((unsigned short)q.w); a7 += bf2f((unsigned short)(q.w >> 16));
        }
        const float dv = dinv[v];
        const float4 bb0 = ((const float4*)b2)[l * 2];
        const float4 bb1 = ((const float4*)b2)[l * 2 + 1];
        float* hp = &hs[n][l * 8];
        hp[0] = fmaxf(fmaf(a0, dv, bb0.x), 0.0f);
        hp[1] = fmaxf(fmaf(a1, dv, bb0.y), 0.0f);
        hp[2] = fmaxf(fmaf(a2, dv, bb0.z), 0.0f);
        hp[3] = fmaxf(fmaf(a3, dv, bb0.w), 0.0f);
        hp[4] = fmaxf(fmaf(a4, dv, bb1.x), 0.0f);
        hp[5] = fmaxf(fmaf(a5, dv, bb1.y), 0.0f);
        hp[6] = fmaxf(fmaf(a6, dv, bb1.z), 0.0f);
        hp[7] = fmaxf(fmaf(a7, dv, bb1.w), 0.0f);
    }
    __syncthreads();
    if (tid < 128) {
        const int vv = blockIdx.x * 128 + tid;
        if (vv < N_NODES) {
            float lg[NC];
#pragma unroll
            for (int j = 0; j < NC; ++j) lg[j] = bcs[j];
#pragma unroll
            for (int k = 0; k < H2; ++k) {
                const float hk = hs[tid][k];
#pragma unroll
                for (int j = 0; j < NC; ++j)
                    lg[j] = fmaf(hk, Wcs[k * NC + j], lg[j]);
            }
            float m = lg[0];
#pragma unroll
            for (int j = 1; j < NC; ++j) m = fmaxf(m, lg[j]);
            float s = 0.0f;
#pragma unroll
            for (int j = 0; j < NC; ++j) s += expf(lg[j] - m);
            const float lse = logf(s) + m;
            float4 o0, o1;
            o0.x = lg[0] - lse; o0.y = lg[1] - lse;
            o0.z = lg[2] - lse; o0.w = lg[3] - lse;
            o1.x = lg[4] - lse; o1.y = lg[5] - lse;
            o1.z = lg[6] - lse; o1.w = lg[7] - lse;
            float4* op = (float4*)(out + (size_t)vv * NC);
            op[0] = o0; op[1] = o1;
        }
    }
}

// ---------------- host launch ----------------

extern "C" void kernel_launch(void* const* d_in, const int* in_sizes, int n_in,
                              void* d_out, int out_size, void* d_ws, size_t ws_size,
                              hipStream_t stream) {
    const float* x   = (const float*)d_in[0];
    const int*   ei  = (const int*)d_in[1];
    const float* W1  = (const float*)d_in[2];
    const float* b1  = (const float*)d_in[3];
    const float* W2  = (const float*)d_in[4];
    const float* b2  = (const float*)d_in[5];
    const float* Wc  = (const float*)d_in[6];
    const float* bc  = (const float*)d_in[7];
    float* out = (float*)d_out;

    // workspace layout (int units). ~43 MB total.
    int*   meta          = (int*)d_ws;                      // 16
    int*   bucket_cursor = meta + 16;                       // 512
    int*   bucket_base   = bucket_cursor + 512;             // 512 (NBUCK+1 used)
    int*   row_ptr       = bucket_base + 512;               // 100016 (100001 used)
    float* dinv          = (float*)(row_ptr + 100016);      // 100000
    unsigned short* W1f  = (unsigned short*)(dinv + 100000);// 4096 bf16 (2048 ints)
    int*   col_idx       = (int*)W1f + 2048;                // 3200000
    int*   ebuf          = col_idx + 3200000;               // NBUCK*BCAP = 6406144
    // u1q (fp8, 3.2 MB) aliases ebuf (dead after k_bfill2); u2b beyond ebuf.
    unsigned int* u1q    = (unsigned int*)ebuf;             // 800000 dwords
    unsigned int* u2b    = (unsigned int*)(ebuf + NBUCK * BCAP); // 800000 dwords

    k_detect  <<<1, 256, 0, stream>>>(ei, W1, meta, bucket_cursor, W1f);
    k_bscatter<<<(N_EDGES + EPB - 1) / EPB, 512, 0, stream>>>(ei, meta, bucket_cursor, ebuf);
    k_bscan   <<<1, 512, 0, stream>>>(bucket_cursor, bucket_base);
    k_bfill2  <<<NBUCK, 512, 0, stream>>>(ebuf, bucket_base, row_ptr, dinv, col_idx);

    k_gemm1m<<<(N_NODES + 63) / 64, 256, 0, stream>>>(x, W1f, dinv, u1q);
    k_pull1f<<<(N_NODES + 63) / 64, 256, 0, stream>>>(row_ptr, col_idx, dinv, u1q, b1, W2, u2b);
    k_pull2f<<<(N_NODES + 127) / 128, 256, 0, stream>>>(row_ptr, col_idx, dinv, u2b, b2, Wc, bc, out);
}

// Round 11
// 223.098 us; speedup vs baseline: 10.0868x; 1.2277x over previous
//
#include <hip/hip_runtime.h>
#include <math.h>

#define N_NODES 100000
#define N_EDGES 3200000
#define D_FEAT 128
#define H1 32
#define H2 16
#define NC 8

#define NBUCK 391          // buckets of 256 dst nodes: ceil(100000/256)
#define BCAP 16384         // fixed ebuf slots per bucket
#define EPB 8192           // edges per k_bscatter block
#define EPT 16             // edges per thread (EPB / 512)

typedef short s16x8 __attribute__((ext_vector_type(8)));
typedef float f32x4 __attribute__((ext_vector_type(4)));

// bf16 helpers (round-to-nearest-even pack, shift-expand)
__device__ inline unsigned short f2bf(float f) {
    unsigned int u = __float_as_uint(f);
    u += 0x7FFF + ((u >> 16) & 1);
    return (unsigned short)(u >> 16);
}
__device__ inline float bf2f(unsigned short h) {
    return __uint_as_float((unsigned int)h << 16);
}

// ---------------- detect edge dtype + zero cursors + W1 B-fragment prep ------

__global__ void k_detect(const int* __restrict__ ei, const float* __restrict__ W1,
                         int* __restrict__ meta, int* __restrict__ bucket_cursor,
                         unsigned short* __restrict__ W1f) {
    __shared__ int red[256];
    int v = 0;
    for (int i = threadIdx.x; i < 1024; i += 256) v |= ei[2 * i + 1];
    red[threadIdx.x] = v;
    __syncthreads();
    for (int s = 128; s > 0; s >>= 1) {
        if (threadIdx.x < (unsigned)s) red[threadIdx.x] |= red[threadIdx.x + s];
        __syncthreads();
    }
    if (threadIdx.x == 0) meta[0] = (red[0] == 0) ? 1 : 0;  // 1 => int64
    for (int i = threadIdx.x; i < NBUCK; i += 256) bucket_cursor[i] = 0;
    for (int idx = threadIdx.x; idx < 2 * 4 * 64 * 8; idx += 256) {
        const int j    = idx & 7;
        const int lane = (idx >> 3) & 63;
        const int kk   = (idx >> 9) & 3;
        const int nt   = idx >> 11;
        const int k = kk * 32 + ((lane >> 4) << 3) + j;
        const int n = nt * 16 + (lane & 15);
        W1f[idx] = f2bf(W1[k * H1 + n]);
    }
}

// ---------------- pass A: bucket scatter via block-local LDS counting sort ---
// Single ei read pass (edges held in registers). Output writes are linear in
// LDS-sorted order -> wave-coalesced full-line stores into per-(block,bucket)
// exclusive segments at region b*BCAP.

__global__ __launch_bounds__(512) void k_bscatter(const int* __restrict__ ei,
                                                  const int* __restrict__ meta,
                                                  int* __restrict__ bucket_cursor,
                                                  int* __restrict__ ebuf) {
    __shared__ int hist[NBUCK];
    __shared__ int lofs[NBUCK];
    __shared__ int rank[NBUCK];
    __shared__ int gb[NBUCK];
    __shared__ int sc[512];
    __shared__ int pay[EPB];                 // 32 KB
    __shared__ unsigned short pbk[EPB];      // 16 KB
    const int tid = threadIdx.x;
    for (int i = tid; i < NBUCK; i += 512) { hist[i] = 0; rank[i] = 0; }
    __syncthreads();
    const int e0 = blockIdx.x * EPB;
    const int n = min(EPB, N_EDGES - e0);
    const bool is64 = (meta[0] != 0);
    int rs[EPT], rd[EPT];
#pragma unroll
    for (int k = 0; k < EPT; ++k) {
        const int i = tid + k * 512;
        if (i < n) {
            const int e = e0 + i;
            if (is64) { rs[k] = ei[2 * e]; rd[k] = ei[2 * N_EDGES + 2 * e]; }
            else      { rs[k] = ei[e];     rd[k] = ei[N_EDGES + e]; }
            atomicAdd(&hist[rd[k] >> 8], 1);
        }
    }
    __syncthreads();
    const int own = (tid < NBUCK) ? hist[tid] : 0;
    sc[tid] = own;
    __syncthreads();
    for (int off = 1; off < 512; off <<= 1) {
        const int v = (tid >= off) ? sc[tid - off] : 0;
        __syncthreads();
        sc[tid] += v;
        __syncthreads();
    }
    if (tid < NBUCK) {
        lofs[tid] = sc[tid] - own;
        if (own > 0) gb[tid] = tid * BCAP + atomicAdd(&bucket_cursor[tid], own);
    }
    __syncthreads();
#pragma unroll
    for (int k = 0; k < EPT; ++k) {
        const int i = tid + k * 512;
        if (i < n) {
            const int b = rd[k] >> 8;
            const int p = lofs[b] + atomicAdd(&rank[b], 1);
            pay[p] = (rs[k] << 8) | (rd[k] & 255);
            pbk[p] = (unsigned short)b;
        }
    }
    __syncthreads();
    for (int p = tid; p < n; p += 512) {
        const int b = pbk[p];
        ebuf[gb[b] + (p - lofs[b])] = pay[p];
    }
}

// ---------------- bucket scan (post-scatter: cursors hold final counts) ------

__global__ __launch_bounds__(512) void k_bscan(const int* __restrict__ bucket_cursor,
                                               int* __restrict__ bucket_base) {
    __shared__ int h[512];
    const int tid = threadIdx.x;
    const int own = (tid < NBUCK) ? bucket_cursor[tid] : 0;
    h[tid] = own;
    __syncthreads();
    for (int off = 1; off < 512; off <<= 1) {
        const int v = (tid >= off) ? h[tid - off] : 0;
        __syncthreads();
        h[tid] += v;
        __syncthreads();
    }
    const int incl = h[tid];
    if (tid < NBUCK) {
        bucket_base[tid] = incl - own;
        if (tid == NBUCK - 1) bucket_base[NBUCK] = incl;  // == N_EDGES
    }
}

// ---------------- pass B: per-bucket degree+scan+fill ----------------

__global__ __launch_bounds__(512) void k_bfill2(const int* __restrict__ ebuf,
                                                const int* __restrict__ bucket_base,
                                                int* __restrict__ row_ptr,
                                                float* __restrict__ dinv,
                                                int* __restrict__ col_idx) {
    __shared__ int cnt[256];
    __shared__ int sc[256];
    __shared__ int cur[256];
    const int b = blockIdx.x;
    const int tid = threadIdx.x;
    if (tid < 256) cnt[tid] = 0;
    __syncthreads();
    const int wb = bucket_base[b];
    const int nb = bucket_base[b + 1] - wb;
    const int rb = b * BCAP;
    for (int i = tid; i < nb; i += 512)
        atomicAdd(&cnt[ebuf[rb + i] & 255], 1);
    __syncthreads();
    int own = 0;
    if (tid < 256) { own = cnt[tid]; sc[tid] = own; }
    __syncthreads();
    for (int off = 1; off < 256; off <<= 1) {
        const int v = (tid < 256 && tid >= off) ? sc[tid - off] : 0;
        __syncthreads();
        if (tid < 256) sc[tid] += v;
        __syncthreads();
    }
    if (tid < 256) {
        const int excl = sc[tid] - own;
        const int v = (b << 8) + tid;
        if (v <= N_NODES) row_ptr[v] = wb + excl;   // v==N_NODES: bucket 390, tid 160
        if (v < N_NODES) dinv[v] = rsqrtf(1.0f + (float)own);  // +1 self-loop
        cur[tid] = wb + excl;
    }
    __syncthreads();
    for (int i = tid; i < nb; i += 512) {
        const int pk = ebuf[rb + i];
        const int slot = atomicAdd(&cur[pk & 255], 1);
        col_idx[slot] = pk >> 8;
    }
}

// ---------------- layer 1 linear via MFMA: u1q = fp8( dinv * (x @ W1) ) ------

__global__ __launch_bounds__(256) void k_gemm1m(const float* __restrict__ x,
                                                const unsigned short* __restrict__ W1f,
                                                const float* __restrict__ dinv,
                                                unsigned int* __restrict__ u1q) {
    __shared__ float os[4][16][33];
    const int tid = threadIdx.x;
    const int w = tid >> 6;
    const int lane = tid & 63;
    const int row0 = (blockIdx.x * 4 + w) * 16;
    const bool act = (row0 < N_NODES);
    if (act) {
        const int m = lane & 15;
        const int quad = lane >> 4;
        const s16x8* bf = (const s16x8*)W1f;
        f32x4 acc0 = {0.f, 0.f, 0.f, 0.f};
        f32x4 acc1 = {0.f, 0.f, 0.f, 0.f};
#pragma unroll
        for (int kk = 0; kk < 4; ++kk) {
            const float* xp = x + (size_t)(row0 + m) * D_FEAT + kk * 32 + quad * 8;
            const float4 p0 = ((const float4*)xp)[0];
            const float4 p1 = ((const float4*)xp)[1];
            s16x8 a;
            a[0] = (short)f2bf(p0.x); a[1] = (short)f2bf(p0.y);
            a[2] = (short)f2bf(p0.z); a[3] = (short)f2bf(p0.w);
            a[4] = (short)f2bf(p1.x); a[5] = (short)f2bf(p1.y);
            a[6] = (short)f2bf(p1.z); a[7] = (short)f2bf(p1.w);
            acc0 = __builtin_amdgcn_mfma_f32_16x16x32_bf16(a, bf[kk * 64 + lane], acc0, 0, 0, 0);
            acc1 = __builtin_amdgcn_mfma_f32_16x16x32_bf16(a, bf[(4 + kk) * 64 + lane], acc1, 0, 0, 0);
        }
#pragma unroll
        for (int r = 0; r < 4; ++r) {
            os[w][quad * 4 + r][m]      = acc0[r];
            os[w][quad * 4 + r][16 + m] = acc1[r];
        }
    }
    __syncthreads();
    if (act) {
        const int rl = lane >> 2;       // row-in-wave 0..15
        const int seg = lane & 3;       // 8-col segment
        const int row = row0 + rl;
        const float dv = dinv[row];
        const float* p = &os[w][rl][seg * 8];
        unsigned int pk0 = __builtin_amdgcn_cvt_pk_fp8_f32(p[0] * dv, p[1] * dv, 0u, false);
        pk0 = __builtin_amdgcn_cvt_pk_fp8_f32(p[2] * dv, p[3] * dv, pk0, true);
        unsigned int pk1 = __builtin_amdgcn_cvt_pk_fp8_f32(p[4] * dv, p[5] * dv, 0u, false);
        pk1 = __builtin_amdgcn_cvt_pk_fp8_f32(p[6] * dv, p[7] * dv, pk1, true);
        uint2 o; o.x = pk0; o.y = pk1;
        ((uint2*)u1q)[(size_t)row * 4 + seg] = o;
    }
}

// ---------------- fused pull1 + GEMM2 (fp8 gather, 4 lanes/node, MLP x4) -----

__global__ __launch_bounds__(256) void k_pull1f(const int* __restrict__ row_ptr,
                                                const int* __restrict__ col_idx,
                                                const float* __restrict__ dinv,
                                                const unsigned int* __restrict__ u1q,
                                                const float* __restrict__ b1,
                                                const float* __restrict__ W2,
                                                unsigned int* __restrict__ u2b) {
    __shared__ float Ws[H1 * H2];   // 512
    __shared__ float hs[64][33];    // padded rows
    const int tid = threadIdx.x;
    for (int i = tid; i < H1 * H2; i += 256) Ws[i] = W2[i];
    const int n = tid >> 2;         // node-in-block 0..63
    const int lq = tid & 3;         // lane 0..3 (8 fp8 = 8B each)
    const int v = blockIdx.x * 64 + n;
    float dv = 0.0f;
    if (v < N_NODES) {
        const uint2* base = (const uint2*)u1q;
        uint2 q = base[(size_t)v * 4 + lq];  // self-loop term
        float a0 = __builtin_amdgcn_cvt_f32_fp8(q.x, 0);
        float a1 = __builtin_amdgcn_cvt_f32_fp8(q.x, 1);
        float a2 = __builtin_amdgcn_cvt_f32_fp8(q.x, 2);
        float a3 = __builtin_amdgcn_cvt_f32_fp8(q.x, 3);
        float a4 = __builtin_amdgcn_cvt_f32_fp8(q.y, 0);
        float a5 = __builtin_amdgcn_cvt_f32_fp8(q.y, 1);
        float a6 = __builtin_amdgcn_cvt_f32_fp8(q.y, 2);
        float a7 = __builtin_amdgcn_cvt_f32_fp8(q.y, 3);
        const int beg = row_ptr[v];
        const int end = row_ptr[v + 1];
        int i = beg;
        for (; i + 4 <= end; i += 4) {   // 4 independent gather chains in flight
            const int s0 = col_idx[i + 0];
            const int s1 = col_idx[i + 1];
            const int s2 = col_idx[i + 2];
            const int s3 = col_idx[i + 3];
            const uint2 q0 = base[(size_t)s0 * 4 + lq];
            const uint2 q1 = base[(size_t)s1 * 4 + lq];
            const uint2 q2 = base[(size_t)s2 * 4 + lq];
            const uint2 q3 = base[(size_t)s3 * 4 + lq];
            a0 += __builtin_amdgcn_cvt_f32_fp8(q0.x, 0) + __builtin_amdgcn_cvt_f32_fp8(q1.x, 0)
                + __builtin_amdgcn_cvt_f32_fp8(q2.x, 0) + __builtin_amdgcn_cvt_f32_fp8(q3.x, 0);
            a1 += __builtin_amdgcn_cvt_f32_fp8(q0.x, 1) + __builtin_amdgcn_cvt_f32_fp8(q1.x, 1)
                + __builtin_amdgcn_cvt_f32_fp8(q2.x, 1) + __builtin_amdgcn_cvt_f32_fp8(q3.x, 1);
            a2 += __builtin_amdgcn_cvt_f32_fp8(q0.x, 2) + __builtin_amdgcn_cvt_f32_fp8(q1.x, 2)
                + __builtin_amdgcn_cvt_f32_fp8(q2.x, 2) + __builtin_amdgcn_cvt_f32_fp8(q3.x, 2);
            a3 += __builtin_amdgcn_cvt_f32_fp8(q0.x, 3) + __builtin_amdgcn_cvt_f32_fp8(q1.x, 3)
                + __builtin_amdgcn_cvt_f32_fp8(q2.x, 3) + __builtin_amdgcn_cvt_f32_fp8(q3.x, 3);
            a4 += __builtin_amdgcn_cvt_f32_fp8(q0.y, 0) + __builtin_amdgcn_cvt_f32_fp8(q1.y, 0)
                + __builtin_amdgcn_cvt_f32_fp8(q2.y, 0) + __builtin_amdgcn_cvt_f32_fp8(q3.y, 0);
            a5 += __builtin_amdgcn_cvt_f32_fp8(q0.y, 1) + __builtin_amdgcn_cvt_f32_fp8(q1.y, 1)
                + __builtin_amdgcn_cvt_f32_fp8(q2.y, 1) + __builtin_amdgcn_cvt_f32_fp8(q3.y, 1);
            a6 += __builtin_amdgcn_cvt_f32_fp8(q0.y, 2) + __builtin_amdgcn_cvt_f32_fp8(q1.y, 2)
                + __builtin_amdgcn_cvt_f32_fp8(q2.y, 2) + __builtin_amdgcn_cvt_f32_fp8(q3.y, 2);
            a7 += __builtin_amdgcn_cvt_f32_fp8(q0.y, 3) + __builtin_amdgcn_cvt_f32_fp8(q1.y, 3)
                + __builtin_amdgcn_cvt_f32_fp8(q2.y, 3) + __builtin_amdgcn_cvt_f32_fp8(q3.y, 3);
        }
        for (; i < end; ++i) {
            const int s = col_idx[i];
            const uint2 qq = base[(size_t)s * 4 + lq];
            a0 += __builtin_amdgcn_cvt_f32_fp8(qq.x, 0);
            a1 += __builtin_amdgcn_cvt_f32_fp8(qq.x, 1);
            a2 += __builtin_amdgcn_cvt_f32_fp8(qq.x, 2);
            a3 += __builtin_amdgcn_cvt_f32_fp8(qq.x, 3);
            a4 += __builtin_amdgcn_cvt_f32_fp8(qq.y, 0);
            a5 += __builtin_amdgcn_cvt_f32_fp8(qq.y, 1);
            a6 += __builtin_amdgcn_cvt_f32_fp8(qq.y, 2);
            a7 += __builtin_amdgcn_cvt_f32_fp8(qq.y, 3);
        }
        dv = dinv[v];
        const float4 bb0 = ((const float4*)b1)[lq * 2];
        const float4 bb1 = ((const float4*)b1)[lq * 2 + 1];
        float* hp = &hs[n][lq * 8];
        hp[0] = fmaxf(fmaf(a0, dv, bb0.x), 0.0f);
        hp[1] = fmaxf(fmaf(a1, dv, bb0.y), 0.0f);
        hp[2] = fmaxf(fmaf(a2, dv, bb0.z), 0.0f);
        hp[3] = fmaxf(fmaf(a3, dv, bb0.w), 0.0f);
        hp[4] = fmaxf(fmaf(a4, dv, bb1.x), 0.0f);
        hp[5] = fmaxf(fmaf(a5, dv, bb1.y), 0.0f);
        hp[6] = fmaxf(fmaf(a6, dv, bb1.z), 0.0f);
        hp[7] = fmaxf(fmaf(a7, dv, bb1.w), 0.0f);
    }
    __syncthreads();
    if (v < N_NODES) {
        const int j0 = lq * 4;
        float s0 = 0.f, s1 = 0.f, s2 = 0.f, s3 = 0.f;
#pragma unroll
        for (int k = 0; k < H1; ++k) {
            const float hk = hs[n][k];
            s0 = fmaf(hk, Ws[k * H2 + j0 + 0], s0);
            s1 = fmaf(hk, Ws[k * H2 + j0 + 1], s1);
            s2 = fmaf(hk, Ws[k * H2 + j0 + 2], s2);
            s3 = fmaf(hk, Ws[k * H2 + j0 + 3], s3);
        }
        uint2 o;
        o.x = (unsigned int)f2bf(s0 * dv) | ((unsigned int)f2bf(s1 * dv) << 16);
        o.y = (unsigned int)f2bf(s2 * dv) | ((unsigned int)f2bf(s3 * dv) << 16);
        ((uint2*)u2b)[(size_t)v * 4 + lq] = o;
    }
}

// ---------------- fused pull2 + classifier (4 lanes/node x 8B, MLP x4) -------

__global__ __launch_bounds__(256) void k_pull2f(const int* __restrict__ row_ptr,
                                                const int* __restrict__ col_idx,
                                                const float* __restrict__ dinv,
                                                const unsigned int* __restrict__ u2b,
                                                const float* __restrict__ b2,
                                                const float* __restrict__ Wc,
                                                const float* __restrict__ bc,
                                                float* __restrict__ out) {
    __shared__ float hs[64][17];    // padded rows
    __shared__ float Wcs[H2 * NC];  // 128
    __shared__ float bcs[NC];
    const int tid = threadIdx.x;
    if (tid < H2 * NC) Wcs[tid] = Wc[tid];
    if (tid < NC) bcs[tid] = bc[tid];
    const int n = tid >> 2;         // node-in-block 0..63
    const int lq = tid & 3;         // lane 0..3 (4 bf16 = 8B each)
    const int v = blockIdx.x * 64 + n;
    if (v < N_NODES) {
        const uint2* base = (const uint2*)u2b;
        uint2 q = base[(size_t)v * 4 + lq];   // self-loop term
        float a0 = bf2f((unsigned short)q.x), a1 = bf2f((unsigned short)(q.x >> 16));
        float a2 = bf2f((unsigned short)q.y), a3 = bf2f((unsigned short)(q.y >> 16));
        const int beg = row_ptr[v];
        const int end = row_ptr[v + 1];
        int i = beg;
        for (; i + 4 <= end; i += 4) {
            const int s0 = col_idx[i + 0];
            const int s1 = col_idx[i + 1];
            const int s2 = col_idx[i + 2];
            const int s3 = col_idx[i + 3];
            const uint2 q0 = base[(size_t)s0 * 4 + lq];
            const uint2 q1 = base[(size_t)s1 * 4 + lq];
            const uint2 q2 = base[(size_t)s2 * 4 + lq];
            const uint2 q3 = base[(size_t)s3 * 4 + lq];
            a0 += bf2f((unsigned short)q0.x) + bf2f((unsigned short)q1.x)
                + bf2f((unsigned short)q2.x) + bf2f((unsigned short)q3.x);
            a1 += bf2f((unsigned short)(q0.x >> 16)) + bf2f((unsigned short)(q1.x >> 16))
                + bf2f((unsigned short)(q2.x >> 16)) + bf2f((unsigned short)(q3.x >> 16));
            a2 += bf2f((unsigned short)q0.y) + bf2f((unsigned short)q1.y)
                + bf2f((unsigned short)q2.y) + bf2f((unsigned short)q3.y);
            a3 += bf2f((unsigned short)(q0.y >> 16)) + bf2f((unsigned short)(q1.y >> 16))
                + bf2f((unsigned short)(q2.y >> 16)) + bf2f((unsigned short)(q3.y >> 16));
        }
        for (; i < end; ++i) {
            const int s = col_idx[i];
            const uint2 qq = base[(size_t)s * 4 + lq];
            a0 += bf2f((unsigned short)qq.x); a1 += bf2f((unsigned short)(qq.x >> 16));
            a2 += bf2f((unsigned short)qq.y); a3 += bf2f((unsigned short)(qq.y >> 16));
        }
        const float dv = dinv[v];
        const float4 bb = ((const float4*)b2)[lq];
        float* hp = &hs[n][lq * 4];
        hp[0] = fmaxf(fmaf(a0, dv, bb.x), 0.0f);
        hp[1] = fmaxf(fmaf(a1, dv, bb.y), 0.0f);
        hp[2] = fmaxf(fmaf(a2, dv, bb.z), 0.0f);
        hp[3] = fmaxf(fmaf(a3, dv, bb.w), 0.0f);
    }
    __syncthreads();
    if (tid < 64) {
        const int vv = blockIdx.x * 64 + tid;
        if (vv < N_NODES) {
            float lg[NC];
#pragma unroll
            for (int j = 0; j < NC; ++j) lg[j] = bcs[j];
#pragma unroll
            for (int k = 0; k < H2; ++k) {
                const float hk = hs[tid][k];
#pragma unroll
                for (int j = 0; j < NC; ++j)
                    lg[j] = fmaf(hk, Wcs[k * NC + j], lg[j]);
            }
            float m = lg[0];
#pragma unroll
            for (int j = 1; j < NC; ++j) m = fmaxf(m, lg[j]);
            float s = 0.0f;
#pragma unroll
            for (int j = 0; j < NC; ++j) s += expf(lg[j] - m);
            const float lse = logf(s) + m;
            float4 o0, o1;
            o0.x = lg[0] - lse; o0.y = lg[1] - lse;
            o0.z = lg[2] - lse; o0.w = lg[3] - lse;
            o1.x = lg[4] - lse; o1.y = lg[5] - lse;
            o1.z = lg[6] - lse; o1.w = lg[7] - lse;
            float4* op = (float4*)(out + (size_t)vv * NC);
            op[0] = o0; op[1] = o1;
        }
    }
}

// ---------------- host launch ----------------

extern "C" void kernel_launch(void* const* d_in, const int* in_sizes, int n_in,
                              void* d_out, int out_size, void* d_ws, size_t ws_size,
                              hipStream_t stream) {
    const float* x   = (const float*)d_in[0];
    const int*   ei  = (const int*)d_in[1];
    const float* W1  = (const float*)d_in[2];
    const float* b1  = (const float*)d_in[3];
    const float* W2  = (const float*)d_in[4];
    const float* b2  = (const float*)d_in[5];
    const float* Wc  = (const float*)d_in[6];
    const float* bc  = (const float*)d_in[7];
    float* out = (float*)d_out;

    // workspace layout (int units). ~43 MB total.
    int*   meta          = (int*)d_ws;                      // 16
    int*   bucket_cursor = meta + 16;                       // 512
    int*   bucket_base   = bucket_cursor + 512;             // 512 (NBUCK+1 used)
    int*   row_ptr       = bucket_base + 512;               // 100016 (100001 used)
    float* dinv          = (float*)(row_ptr + 100016);      // 100000
    unsigned short* W1f  = (unsigned short*)(dinv + 100000);// 4096 bf16 (2048 ints)
    int*   col_idx       = (int*)W1f + 2048;                // 3200000
    int*   ebuf          = col_idx + 3200000;               // NBUCK*BCAP = 6406144
    // u1q (fp8, 3.2 MB) aliases ebuf (dead after k_bfill2); u2b beyond ebuf.
    unsigned int* u1q    = (unsigned int*)ebuf;             // 800000 dwords
    unsigned int* u2b    = (unsigned int*)(ebuf + NBUCK * BCAP); // 800000 dwords

    k_detect  <<<1, 256, 0, stream>>>(ei, W1, meta, bucket_cursor, W1f);
    k_bscatter<<<(N_EDGES + EPB - 1) / EPB, 512, 0, stream>>>(ei, meta, bucket_cursor, ebuf);
    k_bscan   <<<1, 512, 0, stream>>>(bucket_cursor, bucket_base);
    k_bfill2  <<<NBUCK, 512, 0, stream>>>(ebuf, bucket_base, row_ptr, dinv, col_idx);

    k_gemm1m<<<(N_NODES + 63) / 64, 256, 0, stream>>>(x, W1f, dinv, u1q);
    k_pull1f<<<(N_NODES + 63) / 64, 256, 0, stream>>>(row_ptr, col_idx, dinv, u1q, b1, W2, u2b);
    k_pull2f<<<(N_NODES + 63) / 64, 256, 0, stream>>>(row_ptr, col_idx, dinv, u2b, b2, Wc, bc, out);
}